// Round 2
// baseline (5010.400 us; speedup 1.0000x reference)
//
#include <hip/hip_runtime.h>
#include <stdint.h>

#define NB 16
#define WIN 168
#define NSTEPS 24
#define NBLK (4096/NB)
#define NT 512

typedef __attribute__((ext_vector_type(8))) short bf16x8;
typedef __attribute__((ext_vector_type(4))) float f32x4;

#if __has_builtin(__builtin_amdgcn_rcpf)
#define RCPF(x) __builtin_amdgcn_rcpf(x)
#else
#define RCPF(x) (1.0f / (x))
#endif
#if __has_builtin(__builtin_amdgcn_exp2f)
#define EXP2F(x) __builtin_amdgcn_exp2f(x)
#else
#define EXP2F(x) __expf((x) * 0.6931471805599453f)
#endif

__device__ __forceinline__ float sigm(float x){
  return RCPF(1.0f + EXP2F(x * -1.4426950408889634f));
}
__device__ __forceinline__ float sigtanh(float a, float b){
  float A = EXP2F(a * -1.4426950408889634f);
  float B = EXP2F(fabsf(b) * -2.8853900817779268f);
  float t = (1.0f - B) * RCPF((1.0f + A) * (1.0f + B));
  return __builtin_copysignf(t, b);   // t >= 0 always
}

__device__ __forceinline__ uint32_t bf_rn(float f){
  uint32_t u = __builtin_bit_cast(uint32_t, f);
  return (u + 0x7FFFu + ((u >> 16) & 1u)) >> 16;
}
__device__ __forceinline__ float bf_f(uint32_t s){
  return __builtin_bit_cast(float, s << 16);
}
__device__ __forceinline__ void split_t(float f, uint32_t& hi, uint32_t& lo){
  uint32_t u = __builtin_bit_cast(uint32_t, f);
  hi = u >> 16;
  lo = bf_rn(f - bf_f(hi));
}
__device__ __forceinline__ void split_s(float f, short& hi, short& lo){
  uint32_t h = bf_rn(f);
  hi = (short)h;
  lo = (short)bf_rn(f - bf_f(h));
}
// packed f32x2 -> bf16x2 in ONE instruction (RNE). lo16 = bf16(a), hi16 = bf16(b).
__device__ __forceinline__ uint32_t cvtpk2(float a, float b){
  uint32_t r;
  asm("v_cvt_pk_bf16_f32 %0, %1, %2" : "=v"(r) : "v"(a), "v"(b));
  return r;
}
__device__ __forceinline__ float hi_even(uint32_t p){  // f32 of bf16 in low half
  return __builtin_bit_cast(float, p << 16);
}
__device__ __forceinline__ float hi_odd(uint32_t p){   // f32 of bf16 in high half
  return __builtin_bit_cast(float, p & 0xFFFF0000u);
}
__device__ __forceinline__ f32x4 mfma16(bf16x8 a, bf16x8 b, f32x4 c){
  return __builtin_amdgcn_mfma_f32_16x16x32_bf16(a, b, c, 0, 0, 0);
}

#define FROW 136
#define FBLK 544
#define FB(buf,hl,kt) ((((buf)*2 + (hl))*2 + (kt)) * FBLK)
#define BUF_INTS (2*FBLK)

// ============================================================================
// R14 = R13 (4778 us) with the A/B role split MERGED: every wave runs 8 units
// of LSTM1 (2 gate-tiles) AND 8 units of LSTM2 per interval. New tile row map
// ja = 64*(n&3) + 8w + 2*(n>>2) + tu gives each lane all 4 gates of 2
// CONSECUTIVE units -> acc[tu][r] = gate r, and state/hist pair-writes are a
// single dword straight out of v_cvt_pk_bf16_f32. Benefits: perfect 38-MFMA
// wave balance (was 28/48), two independent MFMA+transcendental dep-chains
// per interval (ILP), register c1->c2 handoff (cS deleted), no half-idle
// first/last sweeps, parity-double-buffered hist regs (no shift copies).
// Per-cell math, accumulation order and barrier schedule (168/170/169)
// preserved EXACTLY -> numerics unchanged.
// ============================================================================
__global__ __launch_bounds__(NT, 2) void lstm_fused_kernel(
  const float* __restrict__ x,    const float* __restrict__ Wih1, const float* __restrict__ Whh1,
  const float* __restrict__ bih1, const float* __restrict__ bhh1,
  const float* __restrict__ Wih2, const float* __restrict__ Whh2,
  const float* __restrict__ bih2, const float* __restrict__ bhh2,
  const float* __restrict__ fc1w, const float* __restrict__ fc1b,
  const float* __restrict__ fc2w, const float* __restrict__ fc2b,
  float* __restrict__ out, short* __restrict__ hist)
{
  __shared__ __align__(16) short aS[2*2*2*FBLK];   // LSTM1 state dbuf
  __shared__ __align__(16) short bS[2*2*2*FBLK];   // LSTM2 state dbuf
  __shared__ float win_s[WIN][NB];
  __shared__ float Hlast[NB][68];
  __shared__ float fc1w_s[64*68];
  __shared__ float dval_s[NB];

  const int tid = threadIdx.x;
  const int w   = tid >> 6;          // wave 0..7 (uniform role)
  const int ln  = tid & 63;
  const int q   = ln >> 4;
  const int n   = ln & 15;
  const int bg0 = blockIdx.x * NB;
  const int rdo = q*FROW + n*8;                     // frag read offset (B-operand)
  const int ro  = q*128 + n*8;                      // hist read offset
  const int ktw = w >> 2;                           // this wave's kt for writes
  const int wrw = (w&3)*FROW + n*8 + 2*q;           // state pair-write (short idx, even)
  const int hwo = ktw*512 + (w&3)*128 + n*8 + 2*q;  // hist pair-write (short idx, even)
  short* __restrict__ hblk = hist + (size_t)blockIdx.x * WIN * 2048;

  for (int i = tid; i < WIN*NB; i += NT){ int t = i >> 4, b = i & 15; win_s[t][b] = x[(bg0 + b)*169 + t]; }
  for (int i = tid; i < 64*65; i += NT){ int j = i / 65, k = i % 65; fc1w_s[j*68 + k] = fc1w[i]; }
  if (tid < NB) dval_s[tid] = x[(bg0 + tid)*169 + 168];

  const float fc1b_r = fc1b[ln];
  const float fc2w_r = fc2w[ln];
  const float fc2b_r = fc2b[0];

  // FC head: all 8 waves, 2 batches each.
  auto fc_head = [&](int s){
    float o2[2];
    #pragma unroll
    for (int bi = 0; bi < 2; bi++){
      const int b = 2*w + bi;
      float a1 = fc1b_r;
      #pragma unroll
      for (int k4 = 0; k4 < 16; k4++){
        const float* wp = &fc1w_s[ln*68 + k4*4];
        const float* hp = &Hlast[b][k4*4];
        a1 += wp[0]*hp[0] + wp[1]*hp[1] + wp[2]*hp[2] + wp[3]*hp[3];
      }
      a1 += dval_s[b] * fc1w_s[ln*68 + 64];
      float v = a1 * fc2w_r;
      #pragma unroll
      for (int off = 32; off > 0; off >>= 1) v += __shfl_xor(v, off);
      o2[bi] = v + fc2b_r;
    }
    if (ln == 0){
      #pragma unroll
      for (int bi = 0; bi < 2; bi++){
        const int b = 2*w + bi;
        out[(bg0 + b)*24 + s] = o2[bi];
        win_s[s % WIN][b] = o2[bi];
      }
    }
  };

  // ---- weights: tile tu covers gate g=(row&3), unit 8w + 2*(row>>2) + tu.
  // Lane's A-row index is n -> weight row jA = 64*(n&3) + 8w + 2*(n>>2) + tu.
  // Lane (q,n) output: acc[tu][r] = gate r of unit U = 8w + 2q + tu, batch n.
  bf16x8 A1hi[2][2], A1lo[2][2], Ain1[2];
  bf16x8 A2hi[2][4], A2lo[2][4];
  f32x4 b1c[2], b2c[2];
  #pragma unroll
  for (int tu = 0; tu < 2; tu++){
    const int jA = 64*(n&3) + 8*w + 2*(n>>2) + tu;
    #pragma unroll
    for (int kt = 0; kt < 2; kt++){
      const float* pw = Whh1 + jA*64 + kt*32 + q*8;
      #pragma unroll
      for (int jj = 0; jj < 8; jj++){ short h,l; split_s(pw[jj], h, l); A1hi[tu][kt][jj] = h; A1lo[tu][kt][jj] = l; }
    }
    bf16x8 ain = {0,0,0,0,0,0,0,0};
    if (q == 0){ short wh, wl; split_s(Wih1[jA], wh, wl); ain[0] = wh; ain[1] = wh; ain[2] = wl; }
    Ain1[tu] = ain;
    #pragma unroll
    for (int kt = 0; kt < 4; kt++){
      const float* pw = (kt < 2 ? (Wih2 + jA*64 + kt*32) : (Whh2 + jA*64 + (kt-2)*32)) + q*8;
      #pragma unroll
      for (int jj = 0; jj < 8; jj++){ short h,l; split_s(pw[jj], h, l); A2hi[tu][kt][jj] = h; A2lo[tu][kt][jj] = l; }
    }
    const int U = 8*w + 2*q + tu;
    #pragma unroll
    for (int r = 0; r < 4; r++){
      b1c[tu][r] = bih1[64*r + U] + bhh1[64*r + U];
      b2c[tu][r] = bih2[64*r + U] + bhh2[64*r + U];
    }
  }

  float c1[2], c1sav[2], c2[2];
  bf16x8 hA0, lA0, hA1, lA1, hB0, lB0, hB1, lB1;   // hist operand dbuf (parity)

  auto loadA = [&](int t){
    const short* Hp = hblk + (size_t)t * 2048;
    hA0 = *(const bf16x8*)&Hp[ro];
    lA0 = *(const bf16x8*)&Hp[1024 + ro];
    hA1 = *(const bf16x8*)&Hp[512 + ro];
    lA1 = *(const bf16x8*)&Hp[1536 + ro];
  };
  auto loadB = [&](int t){
    const short* Hp = hblk + (size_t)t * 2048;
    hB0 = *(const bf16x8*)&Hp[ro];
    lB0 = *(const bf16x8*)&Hp[1024 + ro];
    hB1 = *(const bf16x8*)&Hp[512 + ro];
    lB1 = *(const bf16x8*)&Hp[1536 + ro];
  };

  // ---- LSTM1 sub-step (2 units/lane). rb/wb/first compile-time at call sites.
  auto lstm1 = [&](int rb, int wb, int slot, int t, bool first){
    bf16x8 bin = {0,0,0,0,0,0,0,0};
    { float xv = win_s[slot][n];
      uint32_t xp = cvtpk2(xv, xv);
      float rx = xv - hi_even(xp);
      uint32_t xq = cvtpk2(rx, rx);
      if (q == 0){ bin[0] = (short)xp; bin[1] = (short)xq; bin[2] = (short)xp; } }
    f32x4 acc[2];
    if (first){
      #pragma unroll
      for (int tu = 0; tu < 2; tu++) acc[tu] = mfma16(Ain1[tu], bin, b1c[tu]);
    } else {
      bf16x8 Bh0 = *(const bf16x8*)&aS[FB(rb,0,0)+rdo];
      bf16x8 Bl0 = *(const bf16x8*)&aS[FB(rb,1,0)+rdo];
      bf16x8 Bh1 = *(const bf16x8*)&aS[FB(rb,0,1)+rdo];
      bf16x8 Bl1 = *(const bf16x8*)&aS[FB(rb,1,1)+rdo];
      #pragma unroll
      for (int tu = 0; tu < 2; tu++){
        f32x4 a = b1c[tu];
        a = mfma16(A1hi[tu][0], Bh0, a);
        a = mfma16(A1hi[tu][0], Bl0, a);
        a = mfma16(A1lo[tu][0], Bh0, a);
        a = mfma16(A1hi[tu][1], Bh1, a);
        a = mfma16(A1hi[tu][1], Bl1, a);
        a = mfma16(A1lo[tu][1], Bh1, a);
        a = mfma16(Ain1[tu], bin, a);
        acc[tu] = a;
      }
    }
    float hn[2];
    #pragma unroll
    for (int tu = 0; tu < 2; tu++){
      float cn = __builtin_fmaf(sigm(acc[tu][1]), c1[tu], sigtanh(acc[tu][0], acc[tu][2]));
      c1[tu] = cn;
      hn[tu] = sigtanh(acc[tu][3], cn);
    }
    uint32_t p  = cvtpk2(hn[0], hn[1]);
    float r0 = hn[0] - hi_even(p), r1 = hn[1] - hi_odd(p);
    uint32_t ql = cvtpk2(r0, r1);
    *(uint32_t*)&aS[FB(wb,0,ktw)+wrw] = p;
    *(uint32_t*)&aS[FB(wb,1,ktw)+wrw] = ql;
    uint32_t m = (hn[0] > 0.0f ? 0x0000FFFFu : 0u) | (hn[1] > 0.0f ? 0xFFFF0000u : 0u);
    short* Hp = hblk + (size_t)t * 2048;
    *(uint32_t*)&Hp[hwo]        = p  & m;
    *(uint32_t*)&Hp[1024 + hwo] = ql & m;
  };

  // ---- LSTM2 sub-step (2 units/lane). Sr/rb/Sw/wb compile-time at call sites.
  auto lstm2 = [&](bf16x8 h0, bf16x8 l0, bf16x8 h1, bf16x8 l1,
                   const short* Sr, int rb, short* Sw, int wb, bool last){
    bf16x8 Sh0 = *(const bf16x8*)&Sr[FB(rb,0,0)+rdo];
    bf16x8 Sl0 = *(const bf16x8*)&Sr[FB(rb,1,0)+rdo];
    bf16x8 Sh1 = *(const bf16x8*)&Sr[FB(rb,0,1)+rdo];
    bf16x8 Sl1 = *(const bf16x8*)&Sr[FB(rb,1,1)+rdo];
    f32x4 acc[2];
    #pragma unroll
    for (int tu = 0; tu < 2; tu++){
      f32x4 a = b2c[tu];
      a = mfma16(A2hi[tu][0], h0, a);
      a = mfma16(A2hi[tu][0], l0, a);
      a = mfma16(A2lo[tu][0], h0, a);
      a = mfma16(A2hi[tu][1], h1, a);
      a = mfma16(A2hi[tu][1], l1, a);
      a = mfma16(A2lo[tu][1], h1, a);
      a = mfma16(A2hi[tu][2], Sh0, a);
      a = mfma16(A2hi[tu][2], Sl0, a);
      a = mfma16(A2lo[tu][2], Sh0, a);
      a = mfma16(A2hi[tu][3], Sh1, a);
      a = mfma16(A2hi[tu][3], Sl1, a);
      a = mfma16(A2lo[tu][3], Sh1, a);
      acc[tu] = a;
    }
    float hn[2];
    #pragma unroll
    for (int tu = 0; tu < 2; tu++){
      float cn = __builtin_fmaf(sigm(acc[tu][1]), c2[tu], sigtanh(acc[tu][0], acc[tu][2]));
      c2[tu] = cn;
      hn[tu] = sigtanh(acc[tu][3], cn);
    }
    if (!last){
      uint32_t p  = cvtpk2(hn[0], hn[1]);
      float r0 = hn[0] - hi_even(p), r1 = hn[1] - hi_odd(p);
      uint32_t ql = cvtpk2(r0, r1);
      *(uint32_t*)&Sw[FB(wb,0,ktw)+wrw] = p;
      *(uint32_t*)&Sw[FB(wb,1,ktw)+wrw] = ql;
    } else {
      const int U0 = 8*w + 2*q;
      Hlast[n][U0]     = fmaxf(hn[0], 0.0f);
      Hlast[n][U0 + 1] = fmaxf(hn[1], 0.0f);
    }
  };

  // ======================= sweep 0: LSTM1 only. 168 barriers =======================
  c1[0] = 0.0f; c1[1] = 0.0f;
  __syncthreads();
  lstm1(0, 1, 0, 0, true);                          // t=0
  for (int t = 1; t < WIN-1; t += 2){
    __syncthreads();
    lstm1(1, 0, t, t, false);                       // odd t
    __syncthreads();
    lstm1(0, 1, t+1, t+1, false);                   // even t+1
  }
  __syncthreads();
  lstm1(1, 0, WIN-1, WIN-1, false);                 // t=167 -> final h1 in aS[0]
  c1sav[0] = c1[0]; c1sav[1] = c1[1];

  // ===== fused sweeps sg=1..23: LSTM1(sg) + LSTM2(sg-1). 170 barriers each =====
  for (int sg = 1; sg < NSTEPS; sg++){
    c2[0] = c1sav[0]; c2[1] = c1sav[1];             // register c-handoff
    c1[0] = 0.0f;     c1[1] = 0.0f;
    loadA(0); loadB(1);                             // prev sweep's hist (drains at t=0 barrier)
    int slot = sg;
    __syncthreads();                                // t=0
    lstm1(0, 1, slot, 0, true); slot++;
    lstm2(hA0, lA0, hA1, lA1, aS, 0, bS, 1, false); // h2-init from aS[0]
    for (int t = 1; t < WIN-1; t += 2){
      __syncthreads();
      loadA(t + 1);
      lstm1(1, 0, slot, t, false); slot++; if (slot == WIN) slot = 0;
      lstm2(hB0, lB0, hB1, lB1, bS, 1, bS, 0, false);   // odd t
      __syncthreads();
      loadB(t + 2);                                     // t+2 <= 167
      lstm1(0, 1, slot, t+1, false); slot++; if (slot == WIN) slot = 0;
      lstm2(hA0, lA0, hA1, lA1, bS, 0, bS, 1, false);   // even t+1
    }
    __syncthreads();                                // (a)
    lstm2(hB0, lB0, hB1, lB1, bS, 1, bS, 0, true);  // t=167 -> Hlast
    __syncthreads();                                // (b)
    fc_head(sg - 1);
    __syncthreads();                                // (c)
    lstm1(1, 0, slot, WIN-1, false);                // t=167, slot == sg-1 (just updated)
    c1sav[0] = c1[0]; c1sav[1] = c1[1];
  }

  // ============= final sweep: LSTM2(23) only. 169 barriers then FC =============
  {
    c2[0] = c1sav[0]; c2[1] = c1sav[1];
    loadA(0); loadB(1);
    __syncthreads();
    lstm2(hA0, lA0, hA1, lA1, aS, 0, bS, 1, false);
    for (int t = 1; t < WIN-1; t += 2){
      __syncthreads();
      loadA(t + 1);
      lstm2(hB0, lB0, hB1, lB1, bS, 1, bS, 0, false);
      __syncthreads();
      loadB(t + 2);
      lstm2(hA0, lA0, hA1, lA1, bS, 0, bS, 1, false);
    }
    __syncthreads();
    lstm2(hB0, lB0, hB1, lB1, bS, 1, bS, 0, true);  // t=167
    __syncthreads();
    fc_head(NSTEPS - 1);
  }
}

// ============================================================================
// Fallback (no workspace): replay scheme, 256 threads. Safety only.
// ============================================================================
__global__ __launch_bounds__(256, 1) void lstm_fallback_kernel(
  const float* __restrict__ x,    const float* __restrict__ Wih1, const float* __restrict__ Whh1,
  const float* __restrict__ bih1, const float* __restrict__ bhh1,
  const float* __restrict__ Wih2, const float* __restrict__ Whh2,
  const float* __restrict__ bih2, const float* __restrict__ bhh2,
  const float* __restrict__ fc1w, const float* __restrict__ fc1b,
  const float* __restrict__ fc2w, const float* __restrict__ fc2b,
  float* __restrict__ out)
{
  __shared__ __align__(16) short aS[2*2*2*FBLK];
  __shared__ __align__(16) short r1f[2*2*2*FBLK];
  __shared__ __align__(16) short rlf[2*2*2*FBLK];
  __shared__ float win_s[WIN][NB];
  __shared__ float Hlast[NB][68];
  __shared__ float fc1w_s[64*68];
  __shared__ float dval_s[NB];

  const int tid = threadIdx.x;
  const int wv  = tid >> 6;
  const int ln  = tid & 63;
  const int q   = ln >> 4;
  const int n   = ln & 15;
  const int bg0 = blockIdx.x * NB;
  const int u0  = 16*wv + 4*q;
  const int kt_  = u0 >> 5;
  const int q2_  = (u0 >> 3) & 3;
  const int jj0_ = u0 & 7;
  const int rdo  = q*FROW + n*8;
  const int wro  = q2_*FROW + n*8 + jj0_;

  for (int i = tid; i < WIN*NB; i += 256){ int t = i >> 4, b = i & 15; win_s[t][b] = x[(bg0 + b)*169 + t]; }
  for (int i = tid; i < 64*65; i += 256){ int j = i / 65, k = i % 65; fc1w_s[j*68 + k] = fc1w[i]; }
  if (tid < NB) dval_s[tid] = x[(bg0 + tid)*169 + 168];

  const float fc1b_r = fc1b[ln];
  const float fc2w_r = fc2w[ln];
  const float fc2b_r = fc2b[0];

  bf16x8 A1hi[4][2], A1lo[4][2], Ain1[4];
  bf16x8 A2hi[4][4], A2lo[4][4];
  f32x4 b1c[4], b2c[4];
  #pragma unroll
  for (int e = 0; e < 4; e++){
    const int ja = 64*e + 16*wv + n;
    #pragma unroll
    for (int kt = 0; kt < 2; kt++){
      const float* pw = Whh1 + ja*64 + kt*32 + q*8;
      #pragma unroll
      for (int jj = 0; jj < 8; jj++){ short h,l; split_s(pw[jj], h, l); A1hi[e][kt][jj] = h; A1lo[e][kt][jj] = l; }
    }
    #pragma unroll
    for (int kt = 0; kt < 4; kt++){
      const float* pw = (kt < 2 ? (Wih2 + ja*64 + kt*32) : (Whh2 + ja*64 + (kt-2)*32)) + q*8;
      #pragma unroll
      for (int jj = 0; jj < 8; jj++){ short h,l; split_s(pw[jj], h, l); A2hi[e][kt][jj] = h; A2lo[e][kt][jj] = l; }
    }
    bf16x8 ain = {0,0,0,0,0,0,0,0};
    if (q == 0){ short wh, wl; split_s(Wih1[ja], wh, wl); ain[0] = wh; ain[1] = wh; ain[2] = wl; }
    Ain1[e] = ain;
    const int jc = 64*e + u0;
    #pragma unroll
    for (int r = 0; r < 4; r++){
      b1c[e][r] = bih1[jc+r] + bhh1[jc+r];
      b2c[e][r] = bih2[jc+r] + bhh2[jc+r];
    }
  }

  float c1[4], c2[4], c1r[4];

  auto lstm1_step = [&](short* S, float* cst, int rb, int wb, int slot, bool relu_out){
    bf16x8 Bh0 = *(const bf16x8*)&S[FB(rb,0,0)+rdo];
    bf16x8 Bl0 = *(const bf16x8*)&S[FB(rb,1,0)+rdo];
    bf16x8 Bh1 = *(const bf16x8*)&S[FB(rb,0,1)+rdo];
    bf16x8 Bl1 = *(const bf16x8*)&S[FB(rb,1,1)+rdo];
    bf16x8 bin = {0,0,0,0,0,0,0,0};
    { float xv = win_s[slot][n]; uint32_t xh, xl; split_t(xv, xh, xl);
      if (q == 0){ bin[0] = (short)xh; bin[1] = (short)xl; bin[2] = (short)xh; } }
    f32x4 acc[4];
    #pragma unroll
    for (int e = 0; e < 4; e++){
      f32x4 a = b1c[e];
      a = mfma16(A1hi[e][0], Bh0, a);
      a = mfma16(A1hi[e][0], Bl0, a);
      a = mfma16(A1lo[e][0], Bh0, a);
      a = mfma16(A1hi[e][1], Bh1, a);
      a = mfma16(A1hi[e][1], Bl1, a);
      a = mfma16(A1lo[e][1], Bh1, a);
      a = mfma16(Ain1[e], bin, a);
      acc[e] = a;
    }
    float hn[4];
    #pragma unroll
    for (int r = 0; r < 4; r++){
      float cn = __builtin_fmaf(sigm(acc[1][r]), cst[r], sigtanh(acc[0][r], acc[2][r]));
      cst[r] = cn;
      hn[r] = sigtanh(acc[3][r], cn);
    }
    uint32_t ph[4], pl[4];
    #pragma unroll
    for (int r = 0; r < 4; r++) split_t(hn[r], ph[r], pl[r]);
    *(uint2*)&S[FB(wb,0,kt_)+wro] = make_uint2(ph[0] | (ph[1]<<16), ph[2] | (ph[3]<<16));
    *(uint2*)&S[FB(wb,1,kt_)+wro] = make_uint2(pl[0] | (pl[1]<<16), pl[2] | (pl[3]<<16));
    if (relu_out){
      uint32_t sh[4], sl[4];
      #pragma unroll
      for (int r = 0; r < 4; r++){ bool pos = hn[r] > 0.0f; sh[r] = pos ? ph[r] : 0u; sl[r] = pos ? pl[r] : 0u; }
      *(uint2*)&rlf[FB(rb,0,kt_)+wro] = make_uint2(sh[0] | (sh[1]<<16), sh[2] | (sh[3]<<16));
      *(uint2*)&rlf[FB(rb,1,kt_)+wro] = make_uint2(sl[0] | (sl[1]<<16), sl[2] | (sl[3]<<16));
    }
  };

  auto lstm2_core = [&](bf16x8 L1h0, bf16x8 L1l0, bf16x8 L1h1, bf16x8 L1l1,
                        int rbuf, int wbuf, bool last){
    bf16x8 L2h0 = *(const bf16x8*)&aS[FB(rbuf,0,0)+rdo];
    bf16x8 L2l0 = *(const bf16x8*)&aS[FB(rbuf,1,0)+rdo];
    bf16x8 L2h1 = *(const bf16x8*)&aS[FB(rbuf,0,1)+rdo];
    bf16x8 L2l1 = *(const bf16x8*)&aS[FB(rbuf,1,1)+rdo];
    f32x4 acc[4];
    #pragma unroll
    for (int e = 0; e < 4; e++){
      f32x4 a = b2c[e];
      a = mfma16(A2hi[e][0], L1h0, a);
      a = mfma16(A2hi[e][0], L1l0, a);
      a = mfma16(A2lo[e][0], L1h0, a);
      a = mfma16(A2hi[e][1], L1h1, a);
      a = mfma16(A2hi[e][1], L1l1, a);
      a = mfma16(A2lo[e][1], L1h1, a);
      a = mfma16(A2hi[e][2], L2h0, a);
      a = mfma16(A2hi[e][2], L2l0, a);
      a = mfma16(A2lo[e][2], L2h0, a);
      a = mfma16(A2hi[e][3], L2h1, a);
      a = mfma16(A2hi[e][3], L2l1, a);
      a = mfma16(A2lo[e][3], L2h1, a);
      acc[e] = a;
    }
    float hn[4];
    #pragma unroll
    for (int r = 0; r < 4; r++){
      float cn = __builtin_fmaf(sigm(acc[1][r]), c2[r], sigtanh(acc[0][r], acc[2][r]));
      c2[r] = cn;
      hn[r] = sigtanh(acc[3][r], cn);
    }
    if (!last){
      uint32_t ph[4], pl[4];
      #pragma unroll
      for (int r = 0; r < 4; r++) split_t(hn[r], ph[r], pl[r]);
      *(uint2*)&aS[FB(wbuf,0,kt_)+wro] = make_uint2(ph[0] | (ph[1]<<16), ph[2] | (ph[3]<<16));
      *(uint2*)&aS[FB(wbuf,1,kt_)+wro] = make_uint2(pl[0] | (pl[1]<<16), pl[2] | (pl[3]<<16));
    } else {
      #pragma unroll
      for (int r = 0; r < 4; r++) Hlast[n][u0 + r] = fmaxf(hn[r], 0.0f);
    }
  };

  for (int s = 0; s < NSTEPS; s++){
    { int* p = (int*)&aS[0];
      for (int i = tid; i < BUF_INTS; i += 256) p[i] = 0; }
    #pragma unroll
    for (int r = 0; r < 4; r++) c1[r] = 0.0f;
    int slot = s;
    for (int t = 0; t < WIN; t++){
      __syncthreads();
      lstm1_step(aS, c1, t & 1, (t & 1) ^ 1, slot, false);
      slot++; if (slot == WIN) slot = 0;
    }
    #pragma unroll
    for (int r = 0; r < 4; r++){ c2[r] = c1[r]; c1r[r] = 0.0f; }
    { int* p = (int*)&r1f[0];
      for (int i = tid; i < BUF_INTS; i += 256) p[i] = 0; }
    slot = s;
    __syncthreads();
    lstm1_step(r1f, c1r, 0, 1, slot, true);
    slot++;
    for (int i = 1; i < WIN; i++){
      __syncthreads();
      const int rb = i & 1, wb = rb ^ 1;
      lstm1_step(r1f, c1r, rb, wb, slot, true);
      bf16x8 L1h0 = *(const bf16x8*)&rlf[FB(wb,0,0)+rdo];
      bf16x8 L1l0 = *(const bf16x8*)&rlf[FB(wb,1,0)+rdo];
      bf16x8 L1h1 = *(const bf16x8*)&rlf[FB(wb,0,1)+rdo];
      bf16x8 L1l1 = *(const bf16x8*)&rlf[FB(wb,1,1)+rdo];
      lstm2_core(L1h0, L1l0, L1h1, L1l1, wb, rb, false);
      slot++; if (slot == WIN) slot = 0;
    }
    __syncthreads();
    {
      const int rb = (WIN - 1) & 1;
      bf16x8 L1h0 = *(const bf16x8*)&rlf[FB(rb,0,0)+rdo];
      bf16x8 L1l0 = *(const bf16x8*)&rlf[FB(rb,1,0)+rdo];
      bf16x8 L1h1 = *(const bf16x8*)&rlf[FB(rb,0,1)+rdo];
      bf16x8 L1l1 = *(const bf16x8*)&rlf[FB(rb,1,1)+rdo];
      lstm2_core(L1h0, L1l0, L1h1, L1l1, rb, 0, true);
    }
    __syncthreads();
    {
      float o4[4];
      #pragma unroll
      for (int bi = 0; bi < 4; bi++){
        const int b = 4*wv + bi;
        float a1 = fc1b_r;
        #pragma unroll
        for (int k4 = 0; k4 < 16; k4++){
          const float* wp = &fc1w_s[ln*68 + k4*4];
          const float* hp = &Hlast[b][k4*4];
          a1 += wp[0]*hp[0] + wp[1]*hp[1] + wp[2]*hp[2] + wp[3]*hp[3];
        }
        a1 += dval_s[b] * fc1w_s[ln*68 + 64];
        float v = a1 * fc2w_r;
        #pragma unroll
        for (int off = 32; off > 0; off >>= 1) v += __shfl_xor(v, off);
        o4[bi] = v + fc2b_r;
      }
      if (ln == 0){
        #pragma unroll
        for (int bi = 0; bi < 4; bi++){
          const int b = 4*wv + bi;
          out[(bg0 + b)*24 + s] = o4[bi];
          win_s[s % WIN][b] = o4[bi];
        }
      }
    }
  }
}

extern "C" void kernel_launch(void* const* d_in, const int* in_sizes, int n_in,
                              void* d_out, int out_size, void* d_ws, size_t ws_size,
                              hipStream_t stream) {
  (void)in_sizes; (void)n_in; (void)out_size;
  const size_t need = (size_t)NBLK * WIN * 2048 * sizeof(short);   // ~176 MB
  if (ws_size >= need){
    lstm_fused_kernel<<<dim3(NBLK), dim3(NT), 0, stream>>>(
        (const float*)d_in[0], (const float*)d_in[1], (const float*)d_in[2],
        (const float*)d_in[3], (const float*)d_in[4], (const float*)d_in[5],
        (const float*)d_in[6], (const float*)d_in[7], (const float*)d_in[8],
        (const float*)d_in[9], (const float*)d_in[10], (const float*)d_in[11],
        (const float*)d_in[12], (float*)d_out, (short*)d_ws);
  } else {
    lstm_fallback_kernel<<<dim3(NBLK), dim3(256), 0, stream>>>(
        (const float*)d_in[0], (const float*)d_in[1], (const float*)d_in[2],
        (const float*)d_in[3], (const float*)d_in[4], (const float*)d_in[5],
        (const float*)d_in[6], (const float*)d_in[7], (const float*)d_in[8],
        (const float*)d_in[9], (const float*)d_in[10], (const float*)d_in[11],
        (const float*)d_in[12], (float*)d_out);
  }
}

// Round 3
// 4996.298 us; speedup vs baseline: 1.0028x; 1.0028x over previous
//
#include <hip/hip_runtime.h>
#include <stdint.h>

#define NB 16
#define WIN 168
#define NSTEPS 24
#define NBLK (4096/NB)
#define NT 512

typedef __attribute__((ext_vector_type(8))) short bf16x8;
typedef __attribute__((ext_vector_type(4))) float f32x4;

#if __has_builtin(__builtin_amdgcn_rcpf)
#define RCPF(x) __builtin_amdgcn_rcpf(x)
#else
#define RCPF(x) (1.0f / (x))
#endif
#if __has_builtin(__builtin_amdgcn_exp2f)
#define EXP2F(x) __builtin_amdgcn_exp2f(x)
#else
#define EXP2F(x) __expf((x) * 0.6931471805599453f)
#endif

// A-wave barrier: LDS-ordering only. Hist global stores stay in flight across
// the barrier (consumed 168 intervals later; vmcnt window (63) guarantees
// completion long before the reader). B-waves keep __syncthreads(): their
// vmcnt(0) drain before barrier X orders their slot-(t+1) prefetch ahead of
// A's slot-(t+1) store issued after barrier X (hist ring anti-dependency).
#define BAR_A() asm volatile("s_waitcnt lgkmcnt(0)\n\ts_barrier" ::: "memory")
#define BAR_A_FULL() asm volatile("s_waitcnt vmcnt(0) lgkmcnt(0)\n\ts_barrier" ::: "memory")

__device__ __forceinline__ float sigm(float x){
  return RCPF(1.0f + EXP2F(x * -1.4426950408889634f));
}
__device__ __forceinline__ float sigtanh(float a, float b){
  float A = EXP2F(a * -1.4426950408889634f);
  float B = EXP2F(fabsf(b) * -2.8853900817779268f);
  float t = (1.0f - B) * RCPF((1.0f + A) * (1.0f + B));
  return __builtin_copysignf(t, b);   // t >= 0 always
}

__device__ __forceinline__ uint32_t bf_rn(float f){
  uint32_t u = __builtin_bit_cast(uint32_t, f);
  return (u + 0x7FFFu + ((u >> 16) & 1u)) >> 16;
}
__device__ __forceinline__ float bf_f(uint32_t s){
  return __builtin_bit_cast(float, s << 16);
}
__device__ __forceinline__ void split_t(float f, uint32_t& hi, uint32_t& lo){
  uint32_t u = __builtin_bit_cast(uint32_t, f);
  hi = u >> 16;
  lo = bf_rn(f - bf_f(hi));
}
__device__ __forceinline__ void split_s(float f, short& hi, short& lo){
  uint32_t h = bf_rn(f);
  hi = (short)h;
  lo = (short)bf_rn(f - bf_f(h));
}
// packed f32x2 -> bf16x2 in ONE instruction (RNE). lo16 = bf16(a), hi16 = bf16(b).
__device__ __forceinline__ uint32_t cvtpk2(float a, float b){
  uint32_t r;
  asm("v_cvt_pk_bf16_f32 %0, %1, %2" : "=v"(r) : "v"(a), "v"(b));
  return r;
}
__device__ __forceinline__ float hi_even(uint32_t p){  // f32 of bf16 in low half
  return __builtin_bit_cast(float, p << 16);
}
__device__ __forceinline__ float hi_odd(uint32_t p){   // f32 of bf16 in high half
  return __builtin_bit_cast(float, p & 0xFFFF0000u);
}
__device__ __forceinline__ f32x4 mfma16(bf16x8 a, bf16x8 b, f32x4 c){
  return __builtin_amdgcn_mfma_f32_16x16x32_bf16(a, b, c, 0, 0, 0);
}

__device__ __forceinline__ void lstm_epi(const f32x4 acc[4], float c[4], float hn[4]){
  #pragma unroll
  for (int r = 0; r < 4; r++){
    float cn = __builtin_fmaf(sigm(acc[1][r]), c[r], sigtanh(acc[0][r], acc[2][r]));
    c[r] = cn;
    hn[r] = sigtanh(acc[3][r], cn);
  }
}

#define FROW 136
#define FBLK 544
#define FB(buf,hl,kt) ((((buf)*2 + (hl))*2 + (kt)) * FBLK)
#define BUF_INTS (2*FBLK)

// ============================================================================
// R15 = R13 (best: 4778 us; R14 role-merge REVERTED -- it doubled LDS frag
// reads, +66% bank conflicts, +5% time) + role-differentiated barriers:
// A-waves no longer drain vmcnt(0) at every interval barrier (the hist global
// store ack ~300cy/interval was pure stall; data is consumed 168 intervals
// later). B-waves keep __syncthreads() -- their vmcnt(0) drain is the hist
// ring's producer/consumer ordering guard. One full drain per sweep at (a)
// as a release fence. Math/LDS layout/barrier counts identical to R13.
// ============================================================================
__global__ __launch_bounds__(NT, 2) void lstm_fused_kernel(
  const float* __restrict__ x,    const float* __restrict__ Wih1, const float* __restrict__ Whh1,
  const float* __restrict__ bih1, const float* __restrict__ bhh1,
  const float* __restrict__ Wih2, const float* __restrict__ Whh2,
  const float* __restrict__ bih2, const float* __restrict__ bhh2,
  const float* __restrict__ fc1w, const float* __restrict__ fc1b,
  const float* __restrict__ fc2w, const float* __restrict__ fc2b,
  float* __restrict__ out, short* __restrict__ hist)
{
  __shared__ __align__(16) short aS[2*2*2*FBLK];   // LSTM1 state dbuf
  __shared__ __align__(16) short bS[2*2*2*FBLK];   // LSTM2 state dbuf
  __shared__ float cS[64][16];                     // c1-final handoff A->B
  __shared__ float win_s[WIN][NB];
  __shared__ float Hlast[NB][68];
  __shared__ float fc1w_s[64*68];
  __shared__ float dval_s[NB];

  const int tid = threadIdx.x;
  const int wv8 = tid >> 6;          // 0..7
  const int wv  = wv8 & 3;           // role-local wave id 0..3
  const bool isA = (wv8 < 4);
  const int ln  = tid & 63;
  const int q   = ln >> 4;
  const int n   = ln & 15;
  const int bg0 = blockIdx.x * NB;
  const int u0  = 16*wv + 4*q;
  const int kt_  = u0 >> 5;
  const int q2_  = (u0 >> 3) & 3;
  const int jj0_ = u0 & 7;                          // {0,4}
  const int rdo  = q*FROW + n*8;                    // frag read offset
  const int wro  = q2_*FROW + n*8 + jj0_;           // frag write offset
  const int gwo  = kt_*512 + q2_*128 + n*8 + jj0_;  // hist write offset
  const int ro   = q*128 + n*8;                     // hist read offset
  short* __restrict__ hblk = hist + (size_t)blockIdx.x * WIN * 2048;

  for (int i = tid; i < WIN*NB; i += NT){ int t = i >> 4, b = i & 15; win_s[t][b] = x[(bg0 + b)*169 + t]; }
  for (int i = tid; i < 64*65; i += NT){ int j = i / 65, k = i % 65; fc1w_s[j*68 + k] = fc1w[i]; }
  if (tid < NB) dval_s[tid] = x[(bg0 + tid)*169 + 168];

  const float fc1b_r = fc1b[ln];
  const float fc2w_r = fc2w[ln];
  const float fc2b_r = fc2b[0];

  // FC head: all 8 waves, 2 batches each.
  auto fc_head = [&](int s){
    float o2[2];
    #pragma unroll
    for (int bi = 0; bi < 2; bi++){
      const int b = 2*wv8 + bi;
      float a1 = fc1b_r;
      #pragma unroll
      for (int k4 = 0; k4 < 16; k4++){
        const float* wp = &fc1w_s[ln*68 + k4*4];
        const float* hp = &Hlast[b][k4*4];
        a1 += wp[0]*hp[0] + wp[1]*hp[1] + wp[2]*hp[2] + wp[3]*hp[3];
      }
      a1 += dval_s[b] * fc1w_s[ln*68 + 64];
      float v = a1 * fc2w_r;
      #pragma unroll
      for (int off = 32; off > 0; off >>= 1) v += __shfl_xor(v, off);
      o2[bi] = v + fc2b_r;
    }
    if (ln == 0){
      #pragma unroll
      for (int bi = 0; bi < 2; bi++){
        const int b = 2*wv8 + bi;
        out[(bg0 + b)*24 + s] = o2[bi];
        win_s[s % WIN][b] = o2[bi];
      }
    }
  };

  if (isA){
    // =================== A-branch: LSTM1 producer ===================
    bf16x8 A1hi[4][2], A1lo[4][2], Ain1[4];
    f32x4 b1c[4];
    #pragma unroll
    for (int e = 0; e < 4; e++){
      const int ja = 64*e + 16*wv + n;
      #pragma unroll
      for (int kt = 0; kt < 2; kt++){
        const float* pw = Whh1 + ja*64 + kt*32 + q*8;
        #pragma unroll
        for (int jj = 0; jj < 8; jj++){ short h,l; split_s(pw[jj], h, l); A1hi[e][kt][jj] = h; A1lo[e][kt][jj] = l; }
      }
      bf16x8 ain = {0,0,0,0,0,0,0,0};
      if (q == 0){ short wh, wl; split_s(Wih1[ja], wh, wl); ain[0] = wh; ain[1] = wh; ain[2] = wl; }
      Ain1[e] = ain;
      const int jc = 64*e + u0;
      #pragma unroll
      for (int r = 0; r < 4; r++) b1c[e][r] = bih1[jc+r] + bhh1[jc+r];
    }
    float c1[4];

    // rb/wb/first must be compile-time at every call site.
    auto lstm1 = [&](int rb, int wb, int slot, int t, bool first){
      f32x4 acc[4];
      bf16x8 bin = {0,0,0,0,0,0,0,0};
      { float xv = win_s[slot][n];
        uint32_t xp = cvtpk2(xv, xv);
        float rx = xv - hi_even(xp);
        uint32_t xq = cvtpk2(rx, rx);
        if (q == 0){ bin[0] = (short)xp; bin[1] = (short)xq; bin[2] = (short)xp; } }
      if (first){
        #pragma unroll
        for (int e = 0; e < 4; e++) acc[e] = mfma16(Ain1[e], bin, b1c[e]);
      } else {
        bf16x8 Bh0 = *(const bf16x8*)&aS[FB(rb,0,0)+rdo];
        bf16x8 Bl0 = *(const bf16x8*)&aS[FB(rb,1,0)+rdo];
        bf16x8 Bh1 = *(const bf16x8*)&aS[FB(rb,0,1)+rdo];
        bf16x8 Bl1 = *(const bf16x8*)&aS[FB(rb,1,1)+rdo];
        #pragma unroll
        for (int e = 0; e < 4; e++){
          f32x4 a = b1c[e];
          a = mfma16(A1hi[e][0], Bh0, a);
          a = mfma16(A1hi[e][0], Bl0, a);
          a = mfma16(A1lo[e][0], Bh0, a);
          a = mfma16(A1hi[e][1], Bh1, a);
          a = mfma16(A1hi[e][1], Bl1, a);
          a = mfma16(A1lo[e][1], Bh1, a);
          a = mfma16(Ain1[e], bin, a);
          acc[e] = a;
        }
      }
      float hn[4];
      lstm_epi(acc, c1, hn);
      // packed RNE hi/lo split: 2x cvt_pk per half replaces 4x split_t + or/shl packing
      uint32_t p01 = cvtpk2(hn[0], hn[1]);
      uint32_t p23 = cvtpk2(hn[2], hn[3]);
      float r0 = hn[0] - hi_even(p01), r1 = hn[1] - hi_odd(p01);
      float r2 = hn[2] - hi_even(p23), r3 = hn[3] - hi_odd(p23);
      uint32_t q01 = cvtpk2(r0, r1);
      uint32_t q23 = cvtpk2(r2, r3);
      *(uint2*)&aS[FB(wb,0,kt_)+wro] = make_uint2(p01, p23);
      *(uint2*)&aS[FB(wb,1,kt_)+wro] = make_uint2(q01, q23);
      // relu(h) for hist: per-half mask-AND on the packed words
      uint32_t m01 = (hn[0] > 0.0f ? 0x0000FFFFu : 0u) | (hn[1] > 0.0f ? 0xFFFF0000u : 0u);
      uint32_t m23 = (hn[2] > 0.0f ? 0x0000FFFFu : 0u) | (hn[3] > 0.0f ? 0xFFFF0000u : 0u);
      short* Hp = hblk + (size_t)t * 2048;
      *(uint2*)&Hp[gwo]        = make_uint2(p01 & m01, p23 & m23);
      *(uint2*)&Hp[1024 + gwo] = make_uint2(q01 & m01, q23 & m23);
    };

    // ---- sweep 0: A(0) alone. 168 barriers. slot == t.
    #pragma unroll
    for (int r = 0; r < 4; r++) c1[r] = 0.0f;
    BAR_A();
    lstm1(0, 1, 0, 0, true);                          // t=0
    for (int t = 1; t < WIN-1; t += 2){
      BAR_A();
      lstm1(1, 0, t, t, false);                       // odd t
      BAR_A();
      lstm1(0, 1, t+1, t+1, false);                   // even t+1
    }
    BAR_A();
    lstm1(1, 0, WIN-1, WIN-1, false);                 // t=167 -> final h1 in buf0
    #pragma unroll
    for (int r = 0; r < 4; r++) cS[u0 + r][n] = c1[r];

    // ---- fused sweeps sg=1..23. 170 barriers each.
    for (int sg = 1; sg < NSTEPS; sg++){
      #pragma unroll
      for (int r = 0; r < 4; r++) c1[r] = 0.0f;
      int slot = sg;
      BAR_A();                                        // t=0
      lstm1(0, 1, slot, 0, true);
      slot++;
      for (int t = 1; t < WIN-1; t += 2){
        BAR_A();
        lstm1(1, 0, slot, t, false);                  // odd t
        slot++; if (slot == WIN) slot = 0;
        BAR_A();
        lstm1(0, 1, slot, t+1, false);                // even t+1
        slot++; if (slot == WIN) slot = 0;
      }
      BAR_A_FULL();                                   // (a): B does lstm2(167); release fence (1/sweep)
      BAR_A();                                        // (b): Hlast ready
      fc_head(sg - 1);
      BAR_A();                                        // (c): window updated
      lstm1(1, 0, slot, WIN-1, false);                // t=167, slot == sg-1
      #pragma unroll
      for (int r = 0; r < 4; r++) cS[u0 + r][n] = c1[r];
    }

    // ---- final sweep: B(23) alone. 169 barriers then FC.
    for (int i = 0; i < WIN + 1; i++) BAR_A();
    fc_head(NSTEPS - 1);

  } else {
    // =================== B-branch: LSTM2 consumer ===================
    bf16x8 A2hi[4][4], A2lo[4][4];
    f32x4 b2c[4];
    #pragma unroll
    for (int e = 0; e < 4; e++){
      const int ja = 64*e + 16*wv + n;
      #pragma unroll
      for (int kt = 0; kt < 4; kt++){
        const float* pw = (kt < 2 ? (Wih2 + ja*64 + kt*32) : (Whh2 + ja*64 + (kt-2)*32)) + q*8;
        #pragma unroll
        for (int jj = 0; jj < 8; jj++){ short h,l; split_s(pw[jj], h, l); A2hi[e][kt][jj] = h; A2lo[e][kt][jj] = l; }
      }
      const int jc = 64*e + u0;
      #pragma unroll
      for (int r = 0; r < 4; r++) b2c[e][r] = bih2[jc+r] + bhh2[jc+r];
    }
    float c2[4];
    bf16x8 ch0, cl0, ch1, cl1, nh0, nl0, nh1, nl1;

    auto loadc = [&](int t){
      const short* Hp = hblk + (size_t)t * 2048;
      ch0 = *(const bf16x8*)&Hp[ro];
      cl0 = *(const bf16x8*)&Hp[1024 + ro];
      ch1 = *(const bf16x8*)&Hp[512 + ro];
      cl1 = *(const bf16x8*)&Hp[1536 + ro];
    };
    auto loadn = [&](int t){
      const short* Hp = hblk + (size_t)t * 2048;
      nh0 = *(const bf16x8*)&Hp[ro];
      nl0 = *(const bf16x8*)&Hp[1024 + ro];
      nh1 = *(const bf16x8*)&Hp[512 + ro];
      nl1 = *(const bf16x8*)&Hp[1536 + ro];
    };
    auto shift = [&](){ ch0 = nh0; cl0 = nl0; ch1 = nh1; cl1 = nl1; };

    // Sr/rb/Sw/wb must be compile-time at every call site.
    auto lstm2 = [&](const short* Sr, int rb, short* Sw, int wb, bool last){
      bf16x8 L2h0 = *(const bf16x8*)&Sr[FB(rb,0,0)+rdo];
      bf16x8 L2l0 = *(const bf16x8*)&Sr[FB(rb,1,0)+rdo];
      bf16x8 L2h1 = *(const bf16x8*)&Sr[FB(rb,0,1)+rdo];
      bf16x8 L2l1 = *(const bf16x8*)&Sr[FB(rb,1,1)+rdo];
      f32x4 acc[4];
      #pragma unroll
      for (int e = 0; e < 4; e++){
        f32x4 a = b2c[e];
        a = mfma16(A2hi[e][0], ch0, a);
        a = mfma16(A2hi[e][0], cl0, a);
        a = mfma16(A2lo[e][0], ch0, a);
        a = mfma16(A2hi[e][1], ch1, a);
        a = mfma16(A2hi[e][1], cl1, a);
        a = mfma16(A2lo[e][1], ch1, a);
        a = mfma16(A2hi[e][2], L2h0, a);
        a = mfma16(A2hi[e][2], L2l0, a);
        a = mfma16(A2lo[e][2], L2h0, a);
        a = mfma16(A2hi[e][3], L2h1, a);
        a = mfma16(A2hi[e][3], L2l1, a);
        a = mfma16(A2lo[e][3], L2h1, a);
        acc[e] = a;
      }
      float hn[4];
      lstm_epi(acc, c2, hn);
      if (!last){
        uint32_t p01 = cvtpk2(hn[0], hn[1]);
        uint32_t p23 = cvtpk2(hn[2], hn[3]);
        float r0 = hn[0] - hi_even(p01), r1 = hn[1] - hi_odd(p01);
        float r2 = hn[2] - hi_even(p23), r3 = hn[3] - hi_odd(p23);
        *(uint2*)&Sw[FB(wb,0,kt_)+wro] = make_uint2(p01, p23);
        *(uint2*)&Sw[FB(wb,1,kt_)+wro] = make_uint2(cvtpk2(r0, r1), cvtpk2(r2, r3));
      } else {
        #pragma unroll
        for (int r = 0; r < 4; r++) Hlast[n][u0 + r] = fmaxf(hn[r], 0.0f);
      }
    };

    // ---- sweep 0: idle. 168 barriers.
    for (int i = 0; i < WIN; i++) __syncthreads();

    // ---- fused sweeps sg=1..23: B(sg-1). 170 barriers each.
    for (int sg = 1; sg < NSTEPS; sg++){
      loadc(0);                              // sweep seed (drains at t=0 barrier;
      loadn(1);                              // A rewrites slot 0 in interval 0)
      __syncthreads();                       // t=0
      #pragma unroll
      for (int r = 0; r < 4; r++) c2[r] = cS[u0 + r][n];
      lstm2(aS, 0, bS, 1, false);            // t=0: h2-init from aS[0]
      shift();
      for (int t = 1; t < WIN-1; t += 2){
        __syncthreads();
        loadn(t + 1);                        // hoisted prefetch (R9)
        lstm2(bS, 1, bS, 0, false);          // odd t
        shift();
        __syncthreads();
        loadn(t + 2);                        // t+2 <= 167
        lstm2(bS, 0, bS, 1, false);          // even t+1
        shift();
      }
      __syncthreads();                       // (a)
      lstm2(bS, 1, bS, 0, true);             // t=167 -> Hlast
      __syncthreads();                       // (b)
      fc_head(sg - 1);
      __syncthreads();                       // (c)
    }

    // ---- final sweep: B(23). 169 barriers then FC.
    {
      loadc(0);
      loadn(1);
      __syncthreads();
      #pragma unroll
      for (int r = 0; r < 4; r++) c2[r] = cS[u0 + r][n];
      lstm2(aS, 0, bS, 1, false);
      shift();
      for (int t = 1; t < WIN-1; t += 2){
        __syncthreads();
        loadn(t + 1);
        lstm2(bS, 1, bS, 0, false);
        shift();
        __syncthreads();
        loadn(t + 2);
        lstm2(bS, 0, bS, 1, false);
        shift();
      }
      __syncthreads();
      lstm2(bS, 1, bS, 0, true);             // t=167
      __syncthreads();
      fc_head(NSTEPS - 1);
    }
  }
}

// ============================================================================
// Fallback (no workspace): replay scheme, 256 threads. Safety only.
// ============================================================================
__global__ __launch_bounds__(256, 1) void lstm_fallback_kernel(
  const float* __restrict__ x,    const float* __restrict__ Wih1, const float* __restrict__ Whh1,
  const float* __restrict__ bih1, const float* __restrict__ bhh1,
  const float* __restrict__ Wih2, const float* __restrict__ Whh2,
  const float* __restrict__ bih2, const float* __restrict__ bhh2,
  const float* __restrict__ fc1w, const float* __restrict__ fc1b,
  const float* __restrict__ fc2w, const float* __restrict__ fc2b,
  float* __restrict__ out)
{
  __shared__ __align__(16) short aS[2*2*2*FBLK];
  __shared__ __align__(16) short r1f[2*2*2*FBLK];
  __shared__ __align__(16) short rlf[2*2*2*FBLK];
  __shared__ float win_s[WIN][NB];
  __shared__ float Hlast[NB][68];
  __shared__ float fc1w_s[64*68];
  __shared__ float dval_s[NB];

  const int tid = threadIdx.x;
  const int wv  = tid >> 6;
  const int ln  = tid & 63;
  const int q   = ln >> 4;
  const int n   = ln & 15;
  const int bg0 = blockIdx.x * NB;
  const int u0  = 16*wv + 4*q;
  const int kt_  = u0 >> 5;
  const int q2_  = (u0 >> 3) & 3;
  const int jj0_ = u0 & 7;
  const int rdo  = q*FROW + n*8;
  const int wro  = q2_*FROW + n*8 + jj0_;

  for (int i = tid; i < WIN*NB; i += 256){ int t = i >> 4, b = i & 15; win_s[t][b] = x[(bg0 + b)*169 + t]; }
  for (int i = tid; i < 64*65; i += 256){ int j = i / 65, k = i % 65; fc1w_s[j*68 + k] = fc1w[i]; }
  if (tid < NB) dval_s[tid] = x[(bg0 + tid)*169 + 168];

  const float fc1b_r = fc1b[ln];
  const float fc2w_r = fc2w[ln];
  const float fc2b_r = fc2b[0];

  bf16x8 A1hi[4][2], A1lo[4][2], Ain1[4];
  bf16x8 A2hi[4][4], A2lo[4][4];
  f32x4 b1c[4], b2c[4];
  #pragma unroll
  for (int e = 0; e < 4; e++){
    const int ja = 64*e + 16*wv + n;
    #pragma unroll
    for (int kt = 0; kt < 2; kt++){
      const float* pw = Whh1 + ja*64 + kt*32 + q*8;
      #pragma unroll
      for (int jj = 0; jj < 8; jj++){ short h,l; split_s(pw[jj], h, l); A1hi[e][kt][jj] = h; A1lo[e][kt][jj] = l; }
    }
    #pragma unroll
    for (int kt = 0; kt < 4; kt++){
      const float* pw = (kt < 2 ? (Wih2 + ja*64 + kt*32) : (Whh2 + ja*64 + (kt-2)*32)) + q*8;
      #pragma unroll
      for (int jj = 0; jj < 8; jj++){ short h,l; split_s(pw[jj], h, l); A2hi[e][kt][jj] = h; A2lo[e][kt][jj] = l; }
    }
    bf16x8 ain = {0,0,0,0,0,0,0,0};
    if (q == 0){ short wh, wl; split_s(Wih1[ja], wh, wl); ain[0] = wh; ain[1] = wh; ain[2] = wl; }
    Ain1[e] = ain;
    const int jc = 64*e + u0;
    #pragma unroll
    for (int r = 0; r < 4; r++){
      b1c[e][r] = bih1[jc+r] + bhh1[jc+r];
      b2c[e][r] = bih2[jc+r] + bhh2[jc+r];
    }
  }

  float c1[4], c2[4], c1r[4];

  auto lstm1_step = [&](short* S, float* cst, int rb, int wb, int slot, bool relu_out){
    bf16x8 Bh0 = *(const bf16x8*)&S[FB(rb,0,0)+rdo];
    bf16x8 Bl0 = *(const bf16x8*)&S[FB(rb,1,0)+rdo];
    bf16x8 Bh1 = *(const bf16x8*)&S[FB(rb,0,1)+rdo];
    bf16x8 Bl1 = *(const bf16x8*)&S[FB(rb,1,1)+rdo];
    bf16x8 bin = {0,0,0,0,0,0,0,0};
    { float xv = win_s[slot][n]; uint32_t xh, xl; split_t(xv, xh, xl);
      if (q == 0){ bin[0] = (short)xh; bin[1] = (short)xl; bin[2] = (short)xh; } }
    f32x4 acc[4];
    #pragma unroll
    for (int e = 0; e < 4; e++){
      f32x4 a = b1c[e];
      a = mfma16(A1hi[e][0], Bh0, a);
      a = mfma16(A1hi[e][0], Bl0, a);
      a = mfma16(A1lo[e][0], Bh0, a);
      a = mfma16(A1hi[e][1], Bh1, a);
      a = mfma16(A1hi[e][1], Bl1, a);
      a = mfma16(A1lo[e][1], Bh1, a);
      a = mfma16(Ain1[e], bin, a);
      acc[e] = a;
    }
    float hn[4];
    #pragma unroll
    for (int r = 0; r < 4; r++){
      float cn = __builtin_fmaf(sigm(acc[1][r]), cst[r], sigtanh(acc[0][r], acc[2][r]));
      cst[r] = cn;
      hn[r] = sigtanh(acc[3][r], cn);
    }
    uint32_t ph[4], pl[4];
    #pragma unroll
    for (int r = 0; r < 4; r++) split_t(hn[r], ph[r], pl[r]);
    *(uint2*)&S[FB(wb,0,kt_)+wro] = make_uint2(ph[0] | (ph[1]<<16), ph[2] | (ph[3]<<16));
    *(uint2*)&S[FB(wb,1,kt_)+wro] = make_uint2(pl[0] | (pl[1]<<16), pl[2] | (pl[3]<<16));
    if (relu_out){
      uint32_t sh[4], sl[4];
      #pragma unroll
      for (int r = 0; r < 4; r++){ bool pos = hn[r] > 0.0f; sh[r] = pos ? ph[r] : 0u; sl[r] = pos ? pl[r] : 0u; }
      *(uint2*)&rlf[FB(rb,0,kt_)+wro] = make_uint2(sh[0] | (sh[1]<<16), sh[2] | (sh[3]<<16));
      *(uint2*)&rlf[FB(rb,1,kt_)+wro] = make_uint2(sl[0] | (sl[1]<<16), sl[2] | (sl[3]<<16));
    }
  };

  auto lstm2_core = [&](bf16x8 L1h0, bf16x8 L1l0, bf16x8 L1h1, bf16x8 L1l1,
                        int rbuf, int wbuf, bool last){
    bf16x8 L2h0 = *(const bf16x8*)&aS[FB(rbuf,0,0)+rdo];
    bf16x8 L2l0 = *(const bf16x8*)&aS[FB(rbuf,1,0)+rdo];
    bf16x8 L2h1 = *(const bf16x8*)&aS[FB(rbuf,0,1)+rdo];
    bf16x8 L2l1 = *(const bf16x8*)&aS[FB(rbuf,1,1)+rdo];
    f32x4 acc[4];
    #pragma unroll
    for (int e = 0; e < 4; e++){
      f32x4 a = b2c[e];
      a = mfma16(A2hi[e][0], L1h0, a);
      a = mfma16(A2hi[e][0], L1l0, a);
      a = mfma16(A2lo[e][0], L1h0, a);
      a = mfma16(A2hi[e][1], L1h1, a);
      a = mfma16(A2hi[e][1], L1l1, a);
      a = mfma16(A2lo[e][1], L1h1, a);
      a = mfma16(A2hi[e][2], L2h0, a);
      a = mfma16(A2hi[e][2], L2l0, a);
      a = mfma16(A2lo[e][2], L2h0, a);
      a = mfma16(A2hi[e][3], L2h1, a);
      a = mfma16(A2hi[e][3], L2l1, a);
      a = mfma16(A2lo[e][3], L2h1, a);
      acc[e] = a;
    }
    float hn[4];
    #pragma unroll
    for (int r = 0; r < 4; r++){
      float cn = __builtin_fmaf(sigm(acc[1][r]), c2[r], sigtanh(acc[0][r], acc[2][r]));
      c2[r] = cn;
      hn[r] = sigtanh(acc[3][r], cn);
    }
    if (!last){
      uint32_t ph[4], pl[4];
      #pragma unroll
      for (int r = 0; r < 4; r++) split_t(hn[r], ph[r], pl[r]);
      *(uint2*)&aS[FB(wbuf,0,kt_)+wro] = make_uint2(ph[0] | (ph[1]<<16), ph[2] | (ph[3]<<16));
      *(uint2*)&aS[FB(wbuf,1,kt_)+wro] = make_uint2(pl[0] | (pl[1]<<16), pl[2] | (pl[3]<<16));
    } else {
      #pragma unroll
      for (int r = 0; r < 4; r++) Hlast[n][u0 + r] = fmaxf(hn[r], 0.0f);
    }
  };

  for (int s = 0; s < NSTEPS; s++){
    { int* p = (int*)&aS[0];
      for (int i = tid; i < BUF_INTS; i += 256) p[i] = 0; }
    #pragma unroll
    for (int r = 0; r < 4; r++) c1[r] = 0.0f;
    int slot = s;
    for (int t = 0; t < WIN; t++){
      __syncthreads();
      lstm1_step(aS, c1, t & 1, (t & 1) ^ 1, slot, false);
      slot++; if (slot == WIN) slot = 0;
    }
    #pragma unroll
    for (int r = 0; r < 4; r++){ c2[r] = c1[r]; c1r[r] = 0.0f; }
    { int* p = (int*)&r1f[0];
      for (int i = tid; i < BUF_INTS; i += 256) p[i] = 0; }
    slot = s;
    __syncthreads();
    lstm1_step(r1f, c1r, 0, 1, slot, true);
    slot++;
    for (int i = 1; i < WIN; i++){
      __syncthreads();
      const int rb = i & 1, wb = rb ^ 1;
      lstm1_step(r1f, c1r, rb, wb, slot, true);
      bf16x8 L1h0 = *(const bf16x8*)&rlf[FB(wb,0,0)+rdo];
      bf16x8 L1l0 = *(const bf16x8*)&rlf[FB(wb,1,0)+rdo];
      bf16x8 L1h1 = *(const bf16x8*)&rlf[FB(wb,0,1)+rdo];
      bf16x8 L1l1 = *(const bf16x8*)&rlf[FB(wb,1,1)+rdo];
      lstm2_core(L1h0, L1l0, L1h1, L1l1, wb, rb, false);
      slot++; if (slot == WIN) slot = 0;
    }
    __syncthreads();
    {
      const int rb = (WIN - 1) & 1;
      bf16x8 L1h0 = *(const bf16x8*)&rlf[FB(rb,0,0)+rdo];
      bf16x8 L1l0 = *(const bf16x8*)&rlf[FB(rb,1,0)+rdo];
      bf16x8 L1h1 = *(const bf16x8*)&rlf[FB(rb,0,1)+rdo];
      bf16x8 L1l1 = *(const bf16x8*)&rlf[FB(rb,1,1)+rdo];
      lstm2_core(L1h0, L1l0, L1h1, L1l1, rb, 0, true);
    }
    __syncthreads();
    {
      float o4[4];
      #pragma unroll
      for (int bi = 0; bi < 4; bi++){
        const int b = 4*wv + bi;
        float a1 = fc1b_r;
        #pragma unroll
        for (int k4 = 0; k4 < 16; k4++){
          const float* wp = &fc1w_s[ln*68 + k4*4];
          const float* hp = &Hlast[b][k4*4];
          a1 += wp[0]*hp[0] + wp[1]*hp[1] + wp[2]*hp[2] + wp[3]*hp[3];
        }
        a1 += dval_s[b] * fc1w_s[ln*68 + 64];
        float v = a1 * fc2w_r;
        #pragma unroll
        for (int off = 32; off > 0; off >>= 1) v += __shfl_xor(v, off);
        o4[bi] = v + fc2b_r;
      }
      if (ln == 0){
        #pragma unroll
        for (int bi = 0; bi < 4; bi++){
          const int b = 4*wv + bi;
          out[(bg0 + b)*24 + s] = o4[bi];
          win_s[s % WIN][b] = o4[bi];
        }
      }
    }
  }
}

extern "C" void kernel_launch(void* const* d_in, const int* in_sizes, int n_in,
                              void* d_out, int out_size, void* d_ws, size_t ws_size,
                              hipStream_t stream) {
  (void)in_sizes; (void)n_in; (void)out_size;
  const size_t need = (size_t)NBLK * WIN * 2048 * sizeof(short);   // ~176 MB
  if (ws_size >= need){
    lstm_fused_kernel<<<dim3(NBLK), dim3(NT), 0, stream>>>(
        (const float*)d_in[0], (const float*)d_in[1], (const float*)d_in[2],
        (const float*)d_in[3], (const float*)d_in[4], (const float*)d_in[5],
        (const float*)d_in[6], (const float*)d_in[7], (const float*)d_in[8],
        (const float*)d_in[9], (const float*)d_in[10], (const float*)d_in[11],
        (const float*)d_in[12], (float*)d_out, (short*)d_ws);
  } else {
    lstm_fallback_kernel<<<dim3(NBLK), dim3(256), 0, stream>>>(
        (const float*)d_in[0], (const float*)d_in[1], (const float*)d_in[2],
        (const float*)d_in[3], (const float*)d_in[4], (const float*)d_in[5],
        (const float*)d_in[6], (const float*)d_in[7], (const float*)d_in[8],
        (const float*)d_in[9], (const float*)d_in[10], (const float*)d_in[11],
        (const float*)d_in[12], (float*)d_out);
  }
}

// Round 4
// 4956.962 us; speedup vs baseline: 1.0108x; 1.0079x over previous
//
#include <hip/hip_runtime.h>
#include <stdint.h>

#define NB 16
#define WIN 168
#define NSTEPS 24
#define NBLK (4096/NB)
#define NT 1024

typedef __attribute__((ext_vector_type(8))) short bf16x8;
typedef __attribute__((ext_vector_type(4))) float f32x4;

#if __has_builtin(__builtin_amdgcn_rcpf)
#define RCPF(x) __builtin_amdgcn_rcpf(x)
#else
#define RCPF(x) (1.0f / (x))
#endif
#if __has_builtin(__builtin_amdgcn_exp2f)
#define EXP2F(x) __builtin_amdgcn_exp2f(x)
#else
#define EXP2F(x) __expf((x) * 0.6931471805599453f)
#endif

__device__ __forceinline__ float sigm(float x){
  return RCPF(1.0f + EXP2F(x * -1.4426950408889634f));
}
__device__ __forceinline__ float sigtanh(float a, float b){
  float A = EXP2F(a * -1.4426950408889634f);
  float B = EXP2F(fabsf(b) * -2.8853900817779268f);
  float t = (1.0f - B) * RCPF((1.0f + A) * (1.0f + B));
  return __builtin_copysignf(t, b);   // t >= 0 always
}

__device__ __forceinline__ uint32_t bf_rn(float f){
  uint32_t u = __builtin_bit_cast(uint32_t, f);
  return (u + 0x7FFFu + ((u >> 16) & 1u)) >> 16;
}
__device__ __forceinline__ float bf_f(uint32_t s){
  return __builtin_bit_cast(float, s << 16);
}
__device__ __forceinline__ void split_t(float f, uint32_t& hi, uint32_t& lo){
  uint32_t u = __builtin_bit_cast(uint32_t, f);
  hi = u >> 16;
  lo = bf_rn(f - bf_f(hi));
}
__device__ __forceinline__ void split_s(float f, short& hi, short& lo){
  uint32_t h = bf_rn(f);
  hi = (short)h;
  lo = (short)bf_rn(f - bf_f(h));
}
// packed f32x2 -> bf16x2 in ONE instruction (RNE). lo16 = bf16(a), hi16 = bf16(b).
__device__ __forceinline__ uint32_t cvtpk2(float a, float b){
  uint32_t r;
  asm("v_cvt_pk_bf16_f32 %0, %1, %2" : "=v"(r) : "v"(a), "v"(b));
  return r;
}
__device__ __forceinline__ float hi_even(uint32_t p){  // f32 of bf16 in low half
  return __builtin_bit_cast(float, p << 16);
}
__device__ __forceinline__ float hi_odd(uint32_t p){   // f32 of bf16 in high half
  return __builtin_bit_cast(float, p & 0xFFFF0000u);
}
__device__ __forceinline__ f32x4 mfma16(bf16x8 a, bf16x8 b, f32x4 c){
  return __builtin_amdgcn_mfma_f32_16x16x32_bf16(a, b, c, 0, 0, 0);
}

#define FROW 136
#define FBLK 544
#define FB(buf,hl,kt) ((((buf)*2 + (hl))*2 + (kt)) * FBLK)
#define BUF_INTS (2*FBLK)

// ============================================================================
// R16: occupancy attack. R13 schedule (best, 4778 us) kept EXACTLY
// (A/B producer-consumer, 168/170/169 barriers, plain __syncthreads; R15's
// asm barriers reverted -- regressed). Change: 1024-thread blocks, 16 waves.
// Each role split over 8 waves via R14's VERIFIED 2-units-per-lane mapping
// (jA = 64*(n&3) + 8w + 2*(n>>2) + tu): A-wave = 14 MFMA, B-wave = 24 MFMA,
// epilogue halves to 2 units/lane. Rationale: interval ~2800cy vs ~1000cy of
// issue work at 2 waves/SIMD -- latency-bound (ds_read 120cy, 12-deep MFMA
// chains, serial exp->rcp epilogue). 4 waves/SIMD doubles latency hiding.
// B's weight file drops 128->64 VGPR (fully register-resident now).
// Math, accumulation order, and state layouts unchanged -> absmax identical.
// ============================================================================
__global__ __launch_bounds__(NT, 4) void lstm_fused_kernel(
  const float* __restrict__ x,    const float* __restrict__ Wih1, const float* __restrict__ Whh1,
  const float* __restrict__ bih1, const float* __restrict__ bhh1,
  const float* __restrict__ Wih2, const float* __restrict__ Whh2,
  const float* __restrict__ bih2, const float* __restrict__ bhh2,
  const float* __restrict__ fc1w, const float* __restrict__ fc1b,
  const float* __restrict__ fc2w, const float* __restrict__ fc2b,
  float* __restrict__ out, short* __restrict__ hist)
{
  __shared__ __align__(16) short aS[2*2*2*FBLK];   // LSTM1 state dbuf
  __shared__ __align__(16) short bS[2*2*2*FBLK];   // LSTM2 state dbuf
  __shared__ float cS[64][16];                     // c1-final handoff A->B
  __shared__ float win_s[WIN][NB];
  __shared__ float Hlast[NB][68];
  __shared__ float fc1w_s[64*68];
  __shared__ float dval_s[NB];

  const int tid = threadIdx.x;
  const int w16 = tid >> 6;          // 0..15
  const int w   = w16 & 7;           // role-local wave id 0..7
  const bool isA = (w16 < 8);
  const int ln  = tid & 63;
  const int q   = ln >> 4;
  const int n   = ln & 15;
  const int bg0 = blockIdx.x * NB;
  const int rdo = q*FROW + n*8;                     // frag read offset
  const int ro  = q*128 + n*8;                      // hist read offset
  const int ktw = w >> 2;                           // this wave's kt for writes
  const int wrw = (w&3)*FROW + n*8 + 2*q;           // state pair-write (short idx, even)
  const int hwo = ktw*512 + (w&3)*128 + n*8 + 2*q;  // hist pair-write (short idx, even)
  short* __restrict__ hblk = hist + (size_t)blockIdx.x * WIN * 2048;

  for (int i = tid; i < WIN*NB; i += NT){ int t = i >> 4, b = i & 15; win_s[t][b] = x[(bg0 + b)*169 + t]; }
  for (int i = tid; i < 64*65; i += NT){ int j = i / 65, k = i % 65; fc1w_s[j*68 + k] = fc1w[i]; }
  if (tid < NB) dval_s[tid] = x[(bg0 + tid)*169 + 168];

  const float fc1b_r = fc1b[ln];
  const float fc2w_r = fc2w[ln];
  const float fc2b_r = fc2b[0];

  // FC head: 16 waves, 1 batch each.
  auto fc_head = [&](int s){
    const int b = w16;
    float a1 = fc1b_r;
    #pragma unroll
    for (int k4 = 0; k4 < 16; k4++){
      const float* wp = &fc1w_s[ln*68 + k4*4];
      const float* hp = &Hlast[b][k4*4];
      a1 += wp[0]*hp[0] + wp[1]*hp[1] + wp[2]*hp[2] + wp[3]*hp[3];
    }
    a1 += dval_s[b] * fc1w_s[ln*68 + 64];
    float v = a1 * fc2w_r;
    #pragma unroll
    for (int off = 32; off > 0; off >>= 1) v += __shfl_xor(v, off);
    if (ln == 0){
      float o = v + fc2b_r;
      out[(bg0 + b)*24 + s] = o;
      win_s[s % WIN][b] = o;
    }
  };

  if (isA){
    // =================== A-branch: LSTM1 producer (8 waves) ===================
    // Tile tu: lane (q,n) -> acc[tu][r] = gate r of unit U = 8w + 2q + tu, batch n.
    bf16x8 A1hi[2][2], A1lo[2][2], Ain1[2];
    f32x4 b1c[2];
    #pragma unroll
    for (int tu = 0; tu < 2; tu++){
      const int jA = 64*(n&3) + 8*w + 2*(n>>2) + tu;
      #pragma unroll
      for (int kt = 0; kt < 2; kt++){
        const float* pw = Whh1 + jA*64 + kt*32 + q*8;
        #pragma unroll
        for (int jj = 0; jj < 8; jj++){ short h,l; split_s(pw[jj], h, l); A1hi[tu][kt][jj] = h; A1lo[tu][kt][jj] = l; }
      }
      bf16x8 ain = {0,0,0,0,0,0,0,0};
      if (q == 0){ short wh, wl; split_s(Wih1[jA], wh, wl); ain[0] = wh; ain[1] = wh; ain[2] = wl; }
      Ain1[tu] = ain;
      const int U = 8*w + 2*q + tu;
      #pragma unroll
      for (int r = 0; r < 4; r++) b1c[tu][r] = bih1[64*r + U] + bhh1[64*r + U];
    }
    float c1[2];

    // rb/wb/first must be compile-time at every call site.
    auto lstm1 = [&](int rb, int wb, int slot, int t, bool first){
      bf16x8 bin = {0,0,0,0,0,0,0,0};
      { float xv = win_s[slot][n];
        uint32_t xp = cvtpk2(xv, xv);
        float rx = xv - hi_even(xp);
        uint32_t xq = cvtpk2(rx, rx);
        if (q == 0){ bin[0] = (short)xp; bin[1] = (short)xq; bin[2] = (short)xp; } }
      f32x4 acc[2];
      if (first){
        #pragma unroll
        for (int tu = 0; tu < 2; tu++) acc[tu] = mfma16(Ain1[tu], bin, b1c[tu]);
      } else {
        bf16x8 Bh0 = *(const bf16x8*)&aS[FB(rb,0,0)+rdo];
        bf16x8 Bl0 = *(const bf16x8*)&aS[FB(rb,1,0)+rdo];
        bf16x8 Bh1 = *(const bf16x8*)&aS[FB(rb,0,1)+rdo];
        bf16x8 Bl1 = *(const bf16x8*)&aS[FB(rb,1,1)+rdo];
        #pragma unroll
        for (int tu = 0; tu < 2; tu++){
          f32x4 a = b1c[tu];
          a = mfma16(A1hi[tu][0], Bh0, a);
          a = mfma16(A1hi[tu][0], Bl0, a);
          a = mfma16(A1lo[tu][0], Bh0, a);
          a = mfma16(A1hi[tu][1], Bh1, a);
          a = mfma16(A1hi[tu][1], Bl1, a);
          a = mfma16(A1lo[tu][1], Bh1, a);
          a = mfma16(Ain1[tu], bin, a);
          acc[tu] = a;
        }
      }
      float hn[2];
      #pragma unroll
      for (int tu = 0; tu < 2; tu++){
        float cn = __builtin_fmaf(sigm(acc[tu][1]), c1[tu], sigtanh(acc[tu][0], acc[tu][2]));
        c1[tu] = cn;
        hn[tu] = sigtanh(acc[tu][3], cn);
      }
      uint32_t p  = cvtpk2(hn[0], hn[1]);
      float r0 = hn[0] - hi_even(p), r1 = hn[1] - hi_odd(p);
      uint32_t ql = cvtpk2(r0, r1);
      *(uint32_t*)&aS[FB(wb,0,ktw)+wrw] = p;
      *(uint32_t*)&aS[FB(wb,1,ktw)+wrw] = ql;
      uint32_t m = (hn[0] > 0.0f ? 0x0000FFFFu : 0u) | (hn[1] > 0.0f ? 0xFFFF0000u : 0u);
      short* Hp = hblk + (size_t)t * 2048;
      *(uint32_t*)&Hp[hwo]        = p  & m;
      *(uint32_t*)&Hp[1024 + hwo] = ql & m;
    };

    // ---- sweep 0: A(0) alone. 168 barriers. slot == t.
    c1[0] = 0.0f; c1[1] = 0.0f;
    __syncthreads();
    lstm1(0, 1, 0, 0, true);                          // t=0
    for (int t = 1; t < WIN-1; t += 2){
      __syncthreads();
      lstm1(1, 0, t, t, false);                       // odd t
      __syncthreads();
      lstm1(0, 1, t+1, t+1, false);                   // even t+1
    }
    __syncthreads();
    lstm1(1, 0, WIN-1, WIN-1, false);                 // t=167 -> final h1 in buf0
    #pragma unroll
    for (int tu = 0; tu < 2; tu++) cS[8*w + 2*q + tu][n] = c1[tu];

    // ---- fused sweeps sg=1..23. 170 barriers each.
    for (int sg = 1; sg < NSTEPS; sg++){
      c1[0] = 0.0f; c1[1] = 0.0f;
      int slot = sg;
      __syncthreads();                                // t=0
      lstm1(0, 1, slot, 0, true);
      slot++;
      for (int t = 1; t < WIN-1; t += 2){
        __syncthreads();
        lstm1(1, 0, slot, t, false);                  // odd t
        slot++; if (slot == WIN) slot = 0;
        __syncthreads();
        lstm1(0, 1, slot, t+1, false);                // even t+1
        slot++; if (slot == WIN) slot = 0;
      }
      __syncthreads();                                // (a): B does lstm2(167)
      __syncthreads();                                // (b): Hlast ready
      fc_head(sg - 1);
      __syncthreads();                                // (c): window updated
      lstm1(1, 0, slot, WIN-1, false);                // t=167, slot == sg-1
      #pragma unroll
      for (int tu = 0; tu < 2; tu++) cS[8*w + 2*q + tu][n] = c1[tu];
    }

    // ---- final sweep: B(23) alone. 169 barriers then FC.
    for (int i = 0; i < WIN + 1; i++) __syncthreads();
    fc_head(NSTEPS - 1);

  } else {
    // =================== B-branch: LSTM2 consumer (8 waves) ===================
    bf16x8 A2hi[2][4], A2lo[2][4];
    f32x4 b2c[2];
    #pragma unroll
    for (int tu = 0; tu < 2; tu++){
      const int jA = 64*(n&3) + 8*w + 2*(n>>2) + tu;
      #pragma unroll
      for (int kt = 0; kt < 4; kt++){
        const float* pw = (kt < 2 ? (Wih2 + jA*64 + kt*32) : (Whh2 + jA*64 + (kt-2)*32)) + q*8;
        #pragma unroll
        for (int jj = 0; jj < 8; jj++){ short h,l; split_s(pw[jj], h, l); A2hi[tu][kt][jj] = h; A2lo[tu][kt][jj] = l; }
      }
      const int U = 8*w + 2*q + tu;
      #pragma unroll
      for (int r = 0; r < 4; r++) b2c[tu][r] = bih2[64*r + U] + bhh2[64*r + U];
    }
    float c2[2];
    bf16x8 ch0, cl0, ch1, cl1, nh0, nl0, nh1, nl1;

    auto loadc = [&](int t){
      const short* Hp = hblk + (size_t)t * 2048;
      ch0 = *(const bf16x8*)&Hp[ro];
      cl0 = *(const bf16x8*)&Hp[1024 + ro];
      ch1 = *(const bf16x8*)&Hp[512 + ro];
      cl1 = *(const bf16x8*)&Hp[1536 + ro];
    };
    auto loadn = [&](int t){
      const short* Hp = hblk + (size_t)t * 2048;
      nh0 = *(const bf16x8*)&Hp[ro];
      nl0 = *(const bf16x8*)&Hp[1024 + ro];
      nh1 = *(const bf16x8*)&Hp[512 + ro];
      nl1 = *(const bf16x8*)&Hp[1536 + ro];
    };
    auto shift = [&](){ ch0 = nh0; cl0 = nl0; ch1 = nh1; cl1 = nl1; };

    // Sr/rb/Sw/wb must be compile-time at every call site.
    auto lstm2 = [&](const short* Sr, int rb, short* Sw, int wb, bool last){
      bf16x8 Sh0 = *(const bf16x8*)&Sr[FB(rb,0,0)+rdo];
      bf16x8 Sl0 = *(const bf16x8*)&Sr[FB(rb,1,0)+rdo];
      bf16x8 Sh1 = *(const bf16x8*)&Sr[FB(rb,0,1)+rdo];
      bf16x8 Sl1 = *(const bf16x8*)&Sr[FB(rb,1,1)+rdo];
      f32x4 acc[2];
      #pragma unroll
      for (int tu = 0; tu < 2; tu++){
        f32x4 a = b2c[tu];
        a = mfma16(A2hi[tu][0], ch0, a);
        a = mfma16(A2hi[tu][0], cl0, a);
        a = mfma16(A2lo[tu][0], ch0, a);
        a = mfma16(A2hi[tu][1], ch1, a);
        a = mfma16(A2hi[tu][1], cl1, a);
        a = mfma16(A2lo[tu][1], ch1, a);
        a = mfma16(A2hi[tu][2], Sh0, a);
        a = mfma16(A2hi[tu][2], Sl0, a);
        a = mfma16(A2lo[tu][2], Sh0, a);
        a = mfma16(A2hi[tu][3], Sh1, a);
        a = mfma16(A2hi[tu][3], Sl1, a);
        a = mfma16(A2lo[tu][3], Sh1, a);
        acc[tu] = a;
      }
      float hn[2];
      #pragma unroll
      for (int tu = 0; tu < 2; tu++){
        float cn = __builtin_fmaf(sigm(acc[tu][1]), c2[tu], sigtanh(acc[tu][0], acc[tu][2]));
        c2[tu] = cn;
        hn[tu] = sigtanh(acc[tu][3], cn);
      }
      if (!last){
        uint32_t p  = cvtpk2(hn[0], hn[1]);
        float r0 = hn[0] - hi_even(p), r1 = hn[1] - hi_odd(p);
        uint32_t ql = cvtpk2(r0, r1);
        *(uint32_t*)&Sw[FB(wb,0,ktw)+wrw] = p;
        *(uint32_t*)&Sw[FB(wb,1,ktw)+wrw] = ql;
      } else {
        const int U0 = 8*w + 2*q;
        Hlast[n][U0]     = fmaxf(hn[0], 0.0f);
        Hlast[n][U0 + 1] = fmaxf(hn[1], 0.0f);
      }
    };

    // ---- sweep 0: idle. 168 barriers.
    for (int i = 0; i < WIN; i++) __syncthreads();

    // ---- fused sweeps sg=1..23: B(sg-1). 170 barriers each.
    for (int sg = 1; sg < NSTEPS; sg++){
      loadc(0);                              // sweep seed (drains at t=0 barrier;
      loadn(1);                              // A rewrites slot 0 in interval 0)
      __syncthreads();                       // t=0
      #pragma unroll
      for (int tu = 0; tu < 2; tu++) c2[tu] = cS[8*w + 2*q + tu][n];
      lstm2(aS, 0, bS, 1, false);            // t=0: h2-init from aS[0]
      shift();
      for (int t = 1; t < WIN-1; t += 2){
        __syncthreads();
        loadn(t + 1);                        // hoisted prefetch (R9)
        lstm2(bS, 1, bS, 0, false);          // odd t
        shift();
        __syncthreads();
        loadn(t + 2);                        // t+2 <= 167
        lstm2(bS, 0, bS, 1, false);          // even t+1
        shift();
      }
      __syncthreads();                       // (a)
      lstm2(bS, 1, bS, 0, true);             // t=167 -> Hlast
      __syncthreads();                       // (b)
      fc_head(sg - 1);
      __syncthreads();                       // (c)
    }

    // ---- final sweep: B(23). 169 barriers then FC.
    {
      loadc(0);
      loadn(1);
      __syncthreads();
      #pragma unroll
      for (int tu = 0; tu < 2; tu++) c2[tu] = cS[8*w + 2*q + tu][n];
      lstm2(aS, 0, bS, 1, false);
      shift();
      for (int t = 1; t < WIN-1; t += 2){
        __syncthreads();
        loadn(t + 1);
        lstm2(bS, 1, bS, 0, false);
        shift();
        __syncthreads();
        loadn(t + 2);
        lstm2(bS, 0, bS, 1, false);
        shift();
      }
      __syncthreads();
      lstm2(bS, 1, bS, 0, true);             // t=167
      __syncthreads();
      fc_head(NSTEPS - 1);
    }
  }
}

// ============================================================================
// Fallback (no workspace): replay scheme, 256 threads. Safety only.
// ============================================================================
__global__ __launch_bounds__(256, 1) void lstm_fallback_kernel(
  const float* __restrict__ x,    const float* __restrict__ Wih1, const float* __restrict__ Whh1,
  const float* __restrict__ bih1, const float* __restrict__ bhh1,
  const float* __restrict__ Wih2, const float* __restrict__ Whh2,
  const float* __restrict__ bih2, const float* __restrict__ bhh2,
  const float* __restrict__ fc1w, const float* __restrict__ fc1b,
  const float* __restrict__ fc2w, const float* __restrict__ fc2b,
  float* __restrict__ out)
{
  __shared__ __align__(16) short aS[2*2*2*FBLK];
  __shared__ __align__(16) short r1f[2*2*2*FBLK];
  __shared__ __align__(16) short rlf[2*2*2*FBLK];
  __shared__ float win_s[WIN][NB];
  __shared__ float Hlast[NB][68];
  __shared__ float fc1w_s[64*68];
  __shared__ float dval_s[NB];

  const int tid = threadIdx.x;
  const int wv  = tid >> 6;
  const int ln  = tid & 63;
  const int q   = ln >> 4;
  const int n   = ln & 15;
  const int bg0 = blockIdx.x * NB;
  const int u0  = 16*wv + 4*q;
  const int kt_  = u0 >> 5;
  const int q2_  = (u0 >> 3) & 3;
  const int jj0_ = u0 & 7;
  const int rdo  = q*FROW + n*8;
  const int wro  = q2_*FROW + n*8 + jj0_;

  for (int i = tid; i < WIN*NB; i += 256){ int t = i >> 4, b = i & 15; win_s[t][b] = x[(bg0 + b)*169 + t]; }
  for (int i = tid; i < 64*65; i += 256){ int j = i / 65, k = i % 65; fc1w_s[j*68 + k] = fc1w[i]; }
  if (tid < NB) dval_s[tid] = x[(bg0 + tid)*169 + 168];

  const float fc1b_r = fc1b[ln];
  const float fc2w_r = fc2w[ln];
  const float fc2b_r = fc2b[0];

  bf16x8 A1hi[4][2], A1lo[4][2], Ain1[4];
  bf16x8 A2hi[4][4], A2lo[4][4];
  f32x4 b1c[4], b2c[4];
  #pragma unroll
  for (int e = 0; e < 4; e++){
    const int ja = 64*e + 16*wv + n;
    #pragma unroll
    for (int kt = 0; kt < 2; kt++){
      const float* pw = Whh1 + ja*64 + kt*32 + q*8;
      #pragma unroll
      for (int jj = 0; jj < 8; jj++){ short h,l; split_s(pw[jj], h, l); A1hi[e][kt][jj] = h; A1lo[e][kt][jj] = l; }
    }
    #pragma unroll
    for (int kt = 0; kt < 4; kt++){
      const float* pw = (kt < 2 ? (Wih2 + ja*64 + kt*32) : (Whh2 + ja*64 + (kt-2)*32)) + q*8;
      #pragma unroll
      for (int jj = 0; jj < 8; jj++){ short h,l; split_s(pw[jj], h, l); A2hi[e][kt][jj] = h; A2lo[e][kt][jj] = l; }
    }
    bf16x8 ain = {0,0,0,0,0,0,0,0};
    if (q == 0){ short wh, wl; split_s(Wih1[ja], wh, wl); ain[0] = wh; ain[1] = wh; ain[2] = wl; }
    Ain1[e] = ain;
    const int jc = 64*e + u0;
    #pragma unroll
    for (int r = 0; r < 4; r++){
      b1c[e][r] = bih1[jc+r] + bhh1[jc+r];
      b2c[e][r] = bih2[jc+r] + bhh2[jc+r];
    }
  }

  float c1[4], c2[4], c1r[4];

  auto lstm1_step = [&](short* S, float* cst, int rb, int wb, int slot, bool relu_out){
    bf16x8 Bh0 = *(const bf16x8*)&S[FB(rb,0,0)+rdo];
    bf16x8 Bl0 = *(const bf16x8*)&S[FB(rb,1,0)+rdo];
    bf16x8 Bh1 = *(const bf16x8*)&S[FB(rb,0,1)+rdo];
    bf16x8 Bl1 = *(const bf16x8*)&S[FB(rb,1,1)+rdo];
    bf16x8 bin = {0,0,0,0,0,0,0,0};
    { float xv = win_s[slot][n]; uint32_t xh, xl; split_t(xv, xh, xl);
      if (q == 0){ bin[0] = (short)xh; bin[1] = (short)xl; bin[2] = (short)xh; } }
    f32x4 acc[4];
    #pragma unroll
    for (int e = 0; e < 4; e++){
      f32x4 a = b1c[e];
      a = mfma16(A1hi[e][0], Bh0, a);
      a = mfma16(A1hi[e][0], Bl0, a);
      a = mfma16(A1lo[e][0], Bh0, a);
      a = mfma16(A1hi[e][1], Bh1, a);
      a = mfma16(A1hi[e][1], Bl1, a);
      a = mfma16(A1lo[e][1], Bh1, a);
      a = mfma16(Ain1[e], bin, a);
      acc[e] = a;
    }
    float hn[4];
    #pragma unroll
    for (int r = 0; r < 4; r++){
      float cn = __builtin_fmaf(sigm(acc[1][r]), cst[r], sigtanh(acc[0][r], acc[2][r]));
      cst[r] = cn;
      hn[r] = sigtanh(acc[3][r], cn);
    }
    uint32_t ph[4], pl[4];
    #pragma unroll
    for (int r = 0; r < 4; r++) split_t(hn[r], ph[r], pl[r]);
    *(uint2*)&S[FB(wb,0,kt_)+wro] = make_uint2(ph[0] | (ph[1]<<16), ph[2] | (ph[3]<<16));
    *(uint2*)&S[FB(wb,1,kt_)+wro] = make_uint2(pl[0] | (pl[1]<<16), pl[2] | (pl[3]<<16));
    if (relu_out){
      uint32_t sh[4], sl[4];
      #pragma unroll
      for (int r = 0; r < 4; r++){ bool pos = hn[r] > 0.0f; sh[r] = pos ? ph[r] : 0u; sl[r] = pos ? pl[r] : 0u; }
      *(uint2*)&rlf[FB(rb,0,kt_)+wro] = make_uint2(sh[0] | (sh[1]<<16), sh[2] | (sh[3]<<16));
      *(uint2*)&rlf[FB(rb,1,kt_)+wro] = make_uint2(sl[0] | (sl[1]<<16), sl[2] | (sl[3]<<16));
    }
  };

  auto lstm2_core = [&](bf16x8 L1h0, bf16x8 L1l0, bf16x8 L1h1, bf16x8 L1l1,
                        int rbuf, int wbuf, bool last){
    bf16x8 L2h0 = *(const bf16x8*)&aS[FB(rbuf,0,0)+rdo];
    bf16x8 L2l0 = *(const bf16x8*)&aS[FB(rbuf,1,0)+rdo];
    bf16x8 L2h1 = *(const bf16x8*)&aS[FB(rbuf,0,1)+rdo];
    bf16x8 L2l1 = *(const bf16x8*)&aS[FB(rbuf,1,1)+rdo];
    f32x4 acc[4];
    #pragma unroll
    for (int e = 0; e < 4; e++){
      f32x4 a = b2c[e];
      a = mfma16(A2hi[e][0], L1h0, a);
      a = mfma16(A2hi[e][0], L1l0, a);
      a = mfma16(A2lo[e][0], L1h0, a);
      a = mfma16(A2hi[e][1], L1h1, a);
      a = mfma16(A2hi[e][1], L1l1, a);
      a = mfma16(A2lo[e][1], L1h1, a);
      a = mfma16(A2hi[e][2], L2h0, a);
      a = mfma16(A2hi[e][2], L2l0, a);
      a = mfma16(A2lo[e][2], L2h0, a);
      a = mfma16(A2hi[e][3], L2h1, a);
      a = mfma16(A2hi[e][3], L2l1, a);
      a = mfma16(A2lo[e][3], L2h1, a);
      acc[e] = a;
    }
    float hn[4];
    #pragma unroll
    for (int r = 0; r < 4; r++){
      float cn = __builtin_fmaf(sigm(acc[1][r]), c2[r], sigtanh(acc[0][r], acc[2][r]));
      c2[r] = cn;
      hn[r] = sigtanh(acc[3][r], cn);
    }
    if (!last){
      uint32_t ph[4], pl[4];
      #pragma unroll
      for (int r = 0; r < 4; r++) split_t(hn[r], ph[r], pl[r]);
      *(uint2*)&aS[FB(wbuf,0,kt_)+wro] = make_uint2(ph[0] | (ph[1]<<16), ph[2] | (ph[3]<<16));
      *(uint2*)&aS[FB(wbuf,1,kt_)+wro] = make_uint2(pl[0] | (pl[1]<<16), pl[2] | (pl[3]<<16));
    } else {
      #pragma unroll
      for (int r = 0; r < 4; r++) Hlast[n][u0 + r] = fmaxf(hn[r], 0.0f);
    }
  };

  for (int s = 0; s < NSTEPS; s++){
    { int* p = (int*)&aS[0];
      for (int i = tid; i < BUF_INTS; i += 256) p[i] = 0; }
    #pragma unroll
    for (int r = 0; r < 4; r++) c1[r] = 0.0f;
    int slot = s;
    for (int t = 0; t < WIN; t++){
      __syncthreads();
      lstm1_step(aS, c1, t & 1, (t & 1) ^ 1, slot, false);
      slot++; if (slot == WIN) slot = 0;
    }
    #pragma unroll
    for (int r = 0; r < 4; r++){ c2[r] = c1[r]; c1r[r] = 0.0f; }
    { int* p = (int*)&r1f[0];
      for (int i = tid; i < BUF_INTS; i += 256) p[i] = 0; }
    slot = s;
    __syncthreads();
    lstm1_step(r1f, c1r, 0, 1, slot, true);
    slot++;
    for (int i = 1; i < WIN; i++){
      __syncthreads();
      const int rb = i & 1, wb = rb ^ 1;
      lstm1_step(r1f, c1r, rb, wb, slot, true);
      bf16x8 L1h0 = *(const bf16x8*)&rlf[FB(wb,0,0)+rdo];
      bf16x8 L1l0 = *(const bf16x8*)&rlf[FB(wb,1,0)+rdo];
      bf16x8 L1h1 = *(const bf16x8*)&rlf[FB(wb,0,1)+rdo];
      bf16x8 L1l1 = *(const bf16x8*)&rlf[FB(wb,1,1)+rdo];
      lstm2_core(L1h0, L1l0, L1h1, L1l1, wb, rb, false);
      slot++; if (slot == WIN) slot = 0;
    }
    __syncthreads();
    {
      const int rb = (WIN - 1) & 1;
      bf16x8 L1h0 = *(const bf16x8*)&rlf[FB(rb,0,0)+rdo];
      bf16x8 L1l0 = *(const bf16x8*)&rlf[FB(rb,1,0)+rdo];
      bf16x8 L1h1 = *(const bf16x8*)&rlf[FB(rb,0,1)+rdo];
      bf16x8 L1l1 = *(const bf16x8*)&rlf[FB(rb,1,1)+rdo];
      lstm2_core(L1h0, L1l0, L1h1, L1l1, rb, 0, true);
    }
    __syncthreads();
    {
      float o4[4];
      #pragma unroll
      for (int bi = 0; bi < 4; bi++){
        const int b = 4*wv + bi;
        float a1 = fc1b_r;
        #pragma unroll
        for (int k4 = 0; k4 < 16; k4++){
          const float* wp = &fc1w_s[ln*68 + k4*4];
          const float* hp = &Hlast[b][k4*4];
          a1 += wp[0]*hp[0] + wp[1]*hp[1] + wp[2]*hp[2] + wp[3]*hp[3];
        }
        a1 += dval_s[b] * fc1w_s[ln*68 + 64];
        float v = a1 * fc2w_r;
        #pragma unroll
        for (int off = 32; off > 0; off >>= 1) v += __shfl_xor(v, off);
        o4[bi] = v + fc2b_r;
      }
      if (ln == 0){
        #pragma unroll
        for (int bi = 0; bi < 4; bi++){
          const int b = 4*wv + bi;
          out[(bg0 + b)*24 + s] = o4[bi];
          win_s[s % WIN][b] = o4[bi];
        }
      }
    }
  }
}

extern "C" void kernel_launch(void* const* d_in, const int* in_sizes, int n_in,
                              void* d_out, int out_size, void* d_ws, size_t ws_size,
                              hipStream_t stream) {
  (void)in_sizes; (void)n_in; (void)out_size;
  const size_t need = (size_t)NBLK * WIN * 2048 * sizeof(short);   // ~176 MB
  if (ws_size >= need){
    lstm_fused_kernel<<<dim3(NBLK), dim3(NT), 0, stream>>>(
        (const float*)d_in[0], (const float*)d_in[1], (const float*)d_in[2],
        (const float*)d_in[3], (const float*)d_in[4], (const float*)d_in[5],
        (const float*)d_in[6], (const float*)d_in[7], (const float*)d_in[8],
        (const float*)d_in[9], (const float*)d_in[10], (const float*)d_in[11],
        (const float*)d_in[12], (float*)d_out, (short*)d_ws);
  } else {
    lstm_fallback_kernel<<<dim3(NBLK), dim3(256), 0, stream>>>(
        (const float*)d_in[0], (const float*)d_in[1], (const float*)d_in[2],
        (const float*)d_in[3], (const float*)d_in[4], (const float*)d_in[5],
        (const float*)d_in[6], (const float*)d_in[7], (const float*)d_in[8],
        (const float*)d_in[9], (const float*)d_in[10], (const float*)d_in[11],
        (const float*)d_in[12], (float*)d_out);
  }
}

// Round 5
// 4704.529 us; speedup vs baseline: 1.0650x; 1.0537x over previous
//
#include <hip/hip_runtime.h>
#include <stdint.h>

#define NB 16
#define WIN 168
#define NSTEPS 24
#define NBLK (4096/NB)
#define NT 512

typedef __attribute__((ext_vector_type(8))) short bf16x8;
typedef __attribute__((ext_vector_type(4))) float f32x4;
typedef __attribute__((ext_vector_type(2))) float f32x2;

#if __has_builtin(__builtin_amdgcn_rcpf)
#define RCPF(x) __builtin_amdgcn_rcpf(x)
#else
#define RCPF(x) (1.0f / (x))
#endif
#if __has_builtin(__builtin_amdgcn_exp2f)
#define EXP2F(x) __builtin_amdgcn_exp2f(x)
#else
#define EXP2F(x) __expf((x) * 0.6931471805599453f)
#endif

__device__ __forceinline__ float sigm(float x){
  return RCPF(1.0f + EXP2F(x * -1.4426950408889634f));
}
__device__ __forceinline__ float sigtanh(float a, float b){
  float A = EXP2F(a * -1.4426950408889634f);
  float B = EXP2F(fabsf(b) * -2.8853900817779268f);
  float t = (1.0f - B) * RCPF((1.0f + A) * (1.0f + B));
  return __builtin_copysignf(t, b);   // t >= 0 always
}

// ---- packed-f32 (VOP3P v_pk_*) vector helpers: SAME per-lane IEEE ops as the
// scalar versions above, just issued 2-wide. Trans (exp/rcp) stay scalar.
__device__ __forceinline__ f32x2 exp2v(f32x2 x){ return (f32x2){EXP2F(x.x), EXP2F(x.y)}; }
__device__ __forceinline__ f32x2 rcpv(f32x2 x){ return (f32x2){RCPF(x.x), RCPF(x.y)}; }
__device__ __forceinline__ f32x2 absv(f32x2 x){ return (f32x2){fabsf(x.x), fabsf(x.y)}; }
__device__ __forceinline__ f32x2 csignv(f32x2 t, f32x2 s){
  return (f32x2){__builtin_copysignf(t.x, s.x), __builtin_copysignf(t.y, s.y)};
}
__device__ __forceinline__ f32x2 sigmv(f32x2 x){
  return rcpv(1.0f + exp2v(x * -1.4426950408889634f));
}
__device__ __forceinline__ f32x2 sigtanhv(f32x2 a, f32x2 b){
  f32x2 A = exp2v(a * -1.4426950408889634f);
  f32x2 B = exp2v(absv(b) * -2.8853900817779268f);
  f32x2 t = (1.0f - B) * rcpv((1.0f + A) * (1.0f + B));
  return csignv(t, b);
}

__device__ __forceinline__ uint32_t bf_rn(float f){
  uint32_t u = __builtin_bit_cast(uint32_t, f);
  return (u + 0x7FFFu + ((u >> 16) & 1u)) >> 16;
}
__device__ __forceinline__ float bf_f(uint32_t s){
  return __builtin_bit_cast(float, s << 16);
}
__device__ __forceinline__ void split_t(float f, uint32_t& hi, uint32_t& lo){
  uint32_t u = __builtin_bit_cast(uint32_t, f);
  hi = u >> 16;
  lo = bf_rn(f - bf_f(hi));
}
__device__ __forceinline__ void split_s(float f, short& hi, short& lo){
  uint32_t h = bf_rn(f);
  hi = (short)h;
  lo = (short)bf_rn(f - bf_f(h));
}
// packed f32x2 -> bf16x2 in ONE instruction (RNE). lo16 = bf16(a), hi16 = bf16(b).
__device__ __forceinline__ uint32_t cvtpk2(float a, float b){
  uint32_t r;
  asm("v_cvt_pk_bf16_f32 %0, %1, %2" : "=v"(r) : "v"(a), "v"(b));
  return r;
}
__device__ __forceinline__ float hi_even(uint32_t p){  // f32 of bf16 in low half
  return __builtin_bit_cast(float, p << 16);
}
__device__ __forceinline__ float hi_odd(uint32_t p){   // f32 of bf16 in high half
  return __builtin_bit_cast(float, p & 0xFFFF0000u);
}
__device__ __forceinline__ f32x4 mfma16(bf16x8 a, bf16x8 b, f32x4 c){
  return __builtin_amdgcn_mfma_f32_16x16x32_bf16(a, b, c, 0, 0, 0);
}

// R17: packed epilogue -- 2 units per iteration via f32x2 (v_pk_* full-rate
// ops; exp/rcp/copysign stay scalar). Bit-identical math to scalar lstm_epi.
__device__ __forceinline__ void lstm_epi(const f32x4 acc[4], float c[4], float hn[4]){
  #pragma unroll
  for (int p = 0; p < 2; p++){
    const int r0 = 2*p;
    f32x2 gi = {acc[0][r0], acc[0][r0+1]};
    f32x2 gf = {acc[1][r0], acc[1][r0+1]};
    f32x2 gg = {acc[2][r0], acc[2][r0+1]};
    f32x2 go = {acc[3][r0], acc[3][r0+1]};
    f32x2 cc = {c[r0], c[r0+1]};
    f32x2 cn = __builtin_elementwise_fma(sigmv(gf), cc, sigtanhv(gi, gg));
    f32x2 hh = sigtanhv(go, cn);
    c[r0] = cn.x; c[r0+1] = cn.y;
    hn[r0] = hh.x; hn[r0+1] = hh.y;
  }
}

#define FROW 136
#define FBLK 544
#define FB(buf,hl,kt) ((((buf)*2 + (hl))*2 + (kt)) * FBLK)
#define BUF_INTS (2*FBLK)

// ============================================================================
// R17 = R13 (best: 4778 us) + packed-FP32 epilogue. Evidence trail: R14 (more
// issue) regressed, R15 (barrier shave) regressed, R16 (2x occupancy, half
// per-wave work) was NULL at 47% occupancy -- together these pin the limiter
// as SIMD issue-slot saturation, dominated by the LSTM epilogue (trans 4x-rate
// + full-rate FP32). This round cuts the full-rate half via v_pk_*_f32
// (gfx950 VOP3P, IEEE-identical per lane => absmax bit-identical): epilogue
// ~32 -> ~16 full-rate ops per unit-pair, packed bf16-residual subs.
// Schedule, LDS layout, barrier structure, MFMA chains: EXACTLY R13.
// ============================================================================
__global__ __launch_bounds__(NT, 2) void lstm_fused_kernel(
  const float* __restrict__ x,    const float* __restrict__ Wih1, const float* __restrict__ Whh1,
  const float* __restrict__ bih1, const float* __restrict__ bhh1,
  const float* __restrict__ Wih2, const float* __restrict__ Whh2,
  const float* __restrict__ bih2, const float* __restrict__ bhh2,
  const float* __restrict__ fc1w, const float* __restrict__ fc1b,
  const float* __restrict__ fc2w, const float* __restrict__ fc2b,
  float* __restrict__ out, short* __restrict__ hist)
{
  __shared__ __align__(16) short aS[2*2*2*FBLK];   // LSTM1 state dbuf
  __shared__ __align__(16) short bS[2*2*2*FBLK];   // LSTM2 state dbuf
  __shared__ float cS[64][16];                     // c1-final handoff A->B
  __shared__ float win_s[WIN][NB];
  __shared__ float Hlast[NB][68];
  __shared__ float fc1w_s[64*68];
  __shared__ float dval_s[NB];

  const int tid = threadIdx.x;
  const int wv8 = tid >> 6;          // 0..7
  const int wv  = wv8 & 3;           // role-local wave id 0..3
  const bool isA = (wv8 < 4);
  const int ln  = tid & 63;
  const int q   = ln >> 4;
  const int n   = ln & 15;
  const int bg0 = blockIdx.x * NB;
  const int u0  = 16*wv + 4*q;
  const int kt_  = u0 >> 5;
  const int q2_  = (u0 >> 3) & 3;
  const int jj0_ = u0 & 7;                          // {0,4}
  const int rdo  = q*FROW + n*8;                    // frag read offset
  const int wro  = q2_*FROW + n*8 + jj0_;           // frag write offset
  const int gwo  = kt_*512 + q2_*128 + n*8 + jj0_;  // hist write offset
  const int ro   = q*128 + n*8;                     // hist read offset
  short* __restrict__ hblk = hist + (size_t)blockIdx.x * WIN * 2048;

  for (int i = tid; i < WIN*NB; i += NT){ int t = i >> 4, b = i & 15; win_s[t][b] = x[(bg0 + b)*169 + t]; }
  for (int i = tid; i < 64*65; i += NT){ int j = i / 65, k = i % 65; fc1w_s[j*68 + k] = fc1w[i]; }
  if (tid < NB) dval_s[tid] = x[(bg0 + tid)*169 + 168];

  const float fc1b_r = fc1b[ln];
  const float fc2w_r = fc2w[ln];
  const float fc2b_r = fc2b[0];

  // FC head: all 8 waves, 2 batches each.
  auto fc_head = [&](int s){
    float o2[2];
    #pragma unroll
    for (int bi = 0; bi < 2; bi++){
      const int b = 2*wv8 + bi;
      float a1 = fc1b_r;
      #pragma unroll
      for (int k4 = 0; k4 < 16; k4++){
        const float* wp = &fc1w_s[ln*68 + k4*4];
        const float* hp = &Hlast[b][k4*4];
        a1 += wp[0]*hp[0] + wp[1]*hp[1] + wp[2]*hp[2] + wp[3]*hp[3];
      }
      a1 += dval_s[b] * fc1w_s[ln*68 + 64];
      float v = a1 * fc2w_r;
      #pragma unroll
      for (int off = 32; off > 0; off >>= 1) v += __shfl_xor(v, off);
      o2[bi] = v + fc2b_r;
    }
    if (ln == 0){
      #pragma unroll
      for (int bi = 0; bi < 2; bi++){
        const int b = 2*wv8 + bi;
        out[(bg0 + b)*24 + s] = o2[bi];
        win_s[s % WIN][b] = o2[bi];
      }
    }
  };

  if (isA){
    // =================== A-branch: LSTM1 producer ===================
    bf16x8 A1hi[4][2], A1lo[4][2], Ain1[4];
    f32x4 b1c[4];
    #pragma unroll
    for (int e = 0; e < 4; e++){
      const int ja = 64*e + 16*wv + n;
      #pragma unroll
      for (int kt = 0; kt < 2; kt++){
        const float* pw = Whh1 + ja*64 + kt*32 + q*8;
        #pragma unroll
        for (int jj = 0; jj < 8; jj++){ short h,l; split_s(pw[jj], h, l); A1hi[e][kt][jj] = h; A1lo[e][kt][jj] = l; }
      }
      bf16x8 ain = {0,0,0,0,0,0,0,0};
      if (q == 0){ short wh, wl; split_s(Wih1[ja], wh, wl); ain[0] = wh; ain[1] = wh; ain[2] = wl; }
      Ain1[e] = ain;
      const int jc = 64*e + u0;
      #pragma unroll
      for (int r = 0; r < 4; r++) b1c[e][r] = bih1[jc+r] + bhh1[jc+r];
    }
    float c1[4];

    // rb/wb/first must be compile-time at every call site.
    auto lstm1 = [&](int rb, int wb, int slot, int t, bool first){
      f32x4 acc[4];
      bf16x8 bin = {0,0,0,0,0,0,0,0};
      { float xv = win_s[slot][n];
        uint32_t xp = cvtpk2(xv, xv);
        float rx = xv - hi_even(xp);
        uint32_t xq = cvtpk2(rx, rx);
        if (q == 0){ bin[0] = (short)xp; bin[1] = (short)xq; bin[2] = (short)xp; } }
      if (first){
        #pragma unroll
        for (int e = 0; e < 4; e++) acc[e] = mfma16(Ain1[e], bin, b1c[e]);
      } else {
        bf16x8 Bh0 = *(const bf16x8*)&aS[FB(rb,0,0)+rdo];
        bf16x8 Bl0 = *(const bf16x8*)&aS[FB(rb,1,0)+rdo];
        bf16x8 Bh1 = *(const bf16x8*)&aS[FB(rb,0,1)+rdo];
        bf16x8 Bl1 = *(const bf16x8*)&aS[FB(rb,1,1)+rdo];
        #pragma unroll
        for (int e = 0; e < 4; e++){
          f32x4 a = b1c[e];
          a = mfma16(A1hi[e][0], Bh0, a);
          a = mfma16(A1hi[e][0], Bl0, a);
          a = mfma16(A1lo[e][0], Bh0, a);
          a = mfma16(A1hi[e][1], Bh1, a);
          a = mfma16(A1hi[e][1], Bl1, a);
          a = mfma16(A1lo[e][1], Bh1, a);
          a = mfma16(Ain1[e], bin, a);
          acc[e] = a;
        }
      }
      float hn[4];
      lstm_epi(acc, c1, hn);
      // packed RNE hi/lo split: cvt_pk pairs + packed residual subtraction
      uint32_t p01 = cvtpk2(hn[0], hn[1]);
      uint32_t p23 = cvtpk2(hn[2], hn[3]);
      f32x2 r01 = (f32x2){hn[0], hn[1]} - (f32x2){hi_even(p01), hi_odd(p01)};
      f32x2 r23 = (f32x2){hn[2], hn[3]} - (f32x2){hi_even(p23), hi_odd(p23)};
      uint32_t q01 = cvtpk2(r01.x, r01.y);
      uint32_t q23 = cvtpk2(r23.x, r23.y);
      *(uint2*)&aS[FB(wb,0,kt_)+wro] = make_uint2(p01, p23);
      *(uint2*)&aS[FB(wb,1,kt_)+wro] = make_uint2(q01, q23);
      // relu(h) for hist: per-half mask-AND on the packed words
      uint32_t m01 = (hn[0] > 0.0f ? 0x0000FFFFu : 0u) | (hn[1] > 0.0f ? 0xFFFF0000u : 0u);
      uint32_t m23 = (hn[2] > 0.0f ? 0x0000FFFFu : 0u) | (hn[3] > 0.0f ? 0xFFFF0000u : 0u);
      short* Hp = hblk + (size_t)t * 2048;
      *(uint2*)&Hp[gwo]        = make_uint2(p01 & m01, p23 & m23);
      *(uint2*)&Hp[1024 + gwo] = make_uint2(q01 & m01, q23 & m23);
    };

    // ---- sweep 0: A(0) alone. 168 barriers. slot == t.
    #pragma unroll
    for (int r = 0; r < 4; r++) c1[r] = 0.0f;
    __syncthreads();
    lstm1(0, 1, 0, 0, true);                          // t=0
    for (int t = 1; t < WIN-1; t += 2){
      __syncthreads();
      lstm1(1, 0, t, t, false);                       // odd t
      __syncthreads();
      lstm1(0, 1, t+1, t+1, false);                   // even t+1
    }
    __syncthreads();
    lstm1(1, 0, WIN-1, WIN-1, false);                 // t=167 -> final h1 in buf0
    #pragma unroll
    for (int r = 0; r < 4; r++) cS[u0 + r][n] = c1[r];

    // ---- fused sweeps sg=1..23. 170 barriers each.
    for (int sg = 1; sg < NSTEPS; sg++){
      #pragma unroll
      for (int r = 0; r < 4; r++) c1[r] = 0.0f;
      int slot = sg;
      __syncthreads();                                // t=0
      lstm1(0, 1, slot, 0, true);
      slot++;
      for (int t = 1; t < WIN-1; t += 2){
        __syncthreads();
        lstm1(1, 0, slot, t, false);                  // odd t
        slot++; if (slot == WIN) slot = 0;
        __syncthreads();
        lstm1(0, 1, slot, t+1, false);                // even t+1
        slot++; if (slot == WIN) slot = 0;
      }
      __syncthreads();                                // (a): B does lstm2(167)
      __syncthreads();                                // (b): Hlast ready
      fc_head(sg - 1);
      __syncthreads();                                // (c): window updated
      lstm1(1, 0, slot, WIN-1, false);                // t=167, slot == sg-1
      #pragma unroll
      for (int r = 0; r < 4; r++) cS[u0 + r][n] = c1[r];
    }

    // ---- final sweep: B(23) alone. 169 barriers then FC.
    for (int i = 0; i < WIN + 1; i++) __syncthreads();
    fc_head(NSTEPS - 1);

  } else {
    // =================== B-branch: LSTM2 consumer ===================
    bf16x8 A2hi[4][4], A2lo[4][4];
    f32x4 b2c[4];
    #pragma unroll
    for (int e = 0; e < 4; e++){
      const int ja = 64*e + 16*wv + n;
      #pragma unroll
      for (int kt = 0; kt < 4; kt++){
        const float* pw = (kt < 2 ? (Wih2 + ja*64 + kt*32) : (Whh2 + ja*64 + (kt-2)*32)) + q*8;
        #pragma unroll
        for (int jj = 0; jj < 8; jj++){ short h,l; split_s(pw[jj], h, l); A2hi[e][kt][jj] = h; A2lo[e][kt][jj] = l; }
      }
      const int jc = 64*e + u0;
      #pragma unroll
      for (int r = 0; r < 4; r++) b2c[e][r] = bih2[jc+r] + bhh2[jc+r];
    }
    float c2[4];
    bf16x8 ch0, cl0, ch1, cl1, nh0, nl0, nh1, nl1;

    auto loadc = [&](int t){
      const short* Hp = hblk + (size_t)t * 2048;
      ch0 = *(const bf16x8*)&Hp[ro];
      cl0 = *(const bf16x8*)&Hp[1024 + ro];
      ch1 = *(const bf16x8*)&Hp[512 + ro];
      cl1 = *(const bf16x8*)&Hp[1536 + ro];
    };
    auto loadn = [&](int t){
      const short* Hp = hblk + (size_t)t * 2048;
      nh0 = *(const bf16x8*)&Hp[ro];
      nl0 = *(const bf16x8*)&Hp[1024 + ro];
      nh1 = *(const bf16x8*)&Hp[512 + ro];
      nl1 = *(const bf16x8*)&Hp[1536 + ro];
    };
    auto shift = [&](){ ch0 = nh0; cl0 = nl0; ch1 = nh1; cl1 = nl1; };

    // Sr/rb/Sw/wb must be compile-time at every call site.
    auto lstm2 = [&](const short* Sr, int rb, short* Sw, int wb, bool last){
      bf16x8 L2h0 = *(const bf16x8*)&Sr[FB(rb,0,0)+rdo];
      bf16x8 L2l0 = *(const bf16x8*)&Sr[FB(rb,1,0)+rdo];
      bf16x8 L2h1 = *(const bf16x8*)&Sr[FB(rb,0,1)+rdo];
      bf16x8 L2l1 = *(const bf16x8*)&Sr[FB(rb,1,1)+rdo];
      f32x4 acc[4];
      #pragma unroll
      for (int e = 0; e < 4; e++){
        f32x4 a = b2c[e];
        a = mfma16(A2hi[e][0], ch0, a);
        a = mfma16(A2hi[e][0], cl0, a);
        a = mfma16(A2lo[e][0], ch0, a);
        a = mfma16(A2hi[e][1], ch1, a);
        a = mfma16(A2hi[e][1], cl1, a);
        a = mfma16(A2lo[e][1], ch1, a);
        a = mfma16(A2hi[e][2], L2h0, a);
        a = mfma16(A2hi[e][2], L2l0, a);
        a = mfma16(A2lo[e][2], L2h0, a);
        a = mfma16(A2hi[e][3], L2h1, a);
        a = mfma16(A2hi[e][3], L2l1, a);
        a = mfma16(A2lo[e][3], L2h1, a);
        acc[e] = a;
      }
      float hn[4];
      lstm_epi(acc, c2, hn);
      if (!last){
        uint32_t p01 = cvtpk2(hn[0], hn[1]);
        uint32_t p23 = cvtpk2(hn[2], hn[3]);
        f32x2 r01 = (f32x2){hn[0], hn[1]} - (f32x2){hi_even(p01), hi_odd(p01)};
        f32x2 r23 = (f32x2){hn[2], hn[3]} - (f32x2){hi_even(p23), hi_odd(p23)};
        *(uint2*)&Sw[FB(wb,0,kt_)+wro] = make_uint2(p01, p23);
        *(uint2*)&Sw[FB(wb,1,kt_)+wro] = make_uint2(cvtpk2(r01.x, r01.y), cvtpk2(r23.x, r23.y));
      } else {
        #pragma unroll
        for (int r = 0; r < 4; r++) Hlast[n][u0 + r] = fmaxf(hn[r], 0.0f);
      }
    };

    // ---- sweep 0: idle. 168 barriers.
    for (int i = 0; i < WIN; i++) __syncthreads();

    // ---- fused sweeps sg=1..23: B(sg-1). 170 barriers each.
    for (int sg = 1; sg < NSTEPS; sg++){
      loadc(0);                              // sweep seed (drains at t=0 barrier;
      loadn(1);                              // A rewrites slot 0 in interval 0)
      __syncthreads();                       // t=0
      #pragma unroll
      for (int r = 0; r < 4; r++) c2[r] = cS[u0 + r][n];
      lstm2(aS, 0, bS, 1, false);            // t=0: h2-init from aS[0]
      shift();
      for (int t = 1; t < WIN-1; t += 2){
        __syncthreads();
        loadn(t + 1);                        // hoisted prefetch (R9)
        lstm2(bS, 1, bS, 0, false);          // odd t
        shift();
        __syncthreads();
        loadn(t + 2);                        // t+2 <= 167
        lstm2(bS, 0, bS, 1, false);          // even t+1
        shift();
      }
      __syncthreads();                       // (a)
      lstm2(bS, 1, bS, 0, true);             // t=167 -> Hlast
      __syncthreads();                       // (b)
      fc_head(sg - 1);
      __syncthreads();                       // (c)
    }

    // ---- final sweep: B(23). 169 barriers then FC.
    {
      loadc(0);
      loadn(1);
      __syncthreads();
      #pragma unroll
      for (int r = 0; r < 4; r++) c2[r] = cS[u0 + r][n];
      lstm2(aS, 0, bS, 1, false);
      shift();
      for (int t = 1; t < WIN-1; t += 2){
        __syncthreads();
        loadn(t + 1);
        lstm2(bS, 1, bS, 0, false);
        shift();
        __syncthreads();
        loadn(t + 2);
        lstm2(bS, 0, bS, 1, false);
        shift();
      }
      __syncthreads();
      lstm2(bS, 1, bS, 0, true);             // t=167
      __syncthreads();
      fc_head(NSTEPS - 1);
    }
  }
}

// ============================================================================
// Fallback (no workspace): replay scheme, 256 threads. Safety only.
// ============================================================================
__global__ __launch_bounds__(256, 1) void lstm_fallback_kernel(
  const float* __restrict__ x,    const float* __restrict__ Wih1, const float* __restrict__ Whh1,
  const float* __restrict__ bih1, const float* __restrict__ bhh1,
  const float* __restrict__ Wih2, const float* __restrict__ Whh2,
  const float* __restrict__ bih2, const float* __restrict__ bhh2,
  const float* __restrict__ fc1w, const float* __restrict__ fc1b,
  const float* __restrict__ fc2w, const float* __restrict__ fc2b,
  float* __restrict__ out)
{
  __shared__ __align__(16) short aS[2*2*2*FBLK];
  __shared__ __align__(16) short r1f[2*2*2*FBLK];
  __shared__ __align__(16) short rlf[2*2*2*FBLK];
  __shared__ float win_s[WIN][NB];
  __shared__ float Hlast[NB][68];
  __shared__ float fc1w_s[64*68];
  __shared__ float dval_s[NB];

  const int tid = threadIdx.x;
  const int wv  = tid >> 6;
  const int ln  = tid & 63;
  const int q   = ln >> 4;
  const int n   = ln & 15;
  const int bg0 = blockIdx.x * NB;
  const int u0  = 16*wv + 4*q;
  const int kt_  = u0 >> 5;
  const int q2_  = (u0 >> 3) & 3;
  const int jj0_ = u0 & 7;
  const int rdo  = q*FROW + n*8;
  const int wro  = q2_*FROW + n*8 + jj0_;

  for (int i = tid; i < WIN*NB; i += 256){ int t = i >> 4, b = i & 15; win_s[t][b] = x[(bg0 + b)*169 + t]; }
  for (int i = tid; i < 64*65; i += 256){ int j = i / 65, k = i % 65; fc1w_s[j*68 + k] = fc1w[i]; }
  if (tid < NB) dval_s[tid] = x[(bg0 + tid)*169 + 168];

  const float fc1b_r = fc1b[ln];
  const float fc2w_r = fc2w[ln];
  const float fc2b_r = fc2b[0];

  bf16x8 A1hi[4][2], A1lo[4][2], Ain1[4];
  bf16x8 A2hi[4][4], A2lo[4][4];
  f32x4 b1c[4], b2c[4];
  #pragma unroll
  for (int e = 0; e < 4; e++){
    const int ja = 64*e + 16*wv + n;
    #pragma unroll
    for (int kt = 0; kt < 2; kt++){
      const float* pw = Whh1 + ja*64 + kt*32 + q*8;
      #pragma unroll
      for (int jj = 0; jj < 8; jj++){ short h,l; split_s(pw[jj], h, l); A1hi[e][kt][jj] = h; A1lo[e][kt][jj] = l; }
    }
    #pragma unroll
    for (int kt = 0; kt < 4; kt++){
      const float* pw = (kt < 2 ? (Wih2 + ja*64 + kt*32) : (Whh2 + ja*64 + (kt-2)*32)) + q*8;
      #pragma unroll
      for (int jj = 0; jj < 8; jj++){ short h,l; split_s(pw[jj], h, l); A2hi[e][kt][jj] = h; A2lo[e][kt][jj] = l; }
    }
    bf16x8 ain = {0,0,0,0,0,0,0,0};
    if (q == 0){ short wh, wl; split_s(Wih1[ja], wh, wl); ain[0] = wh; ain[1] = wh; ain[2] = wl; }
    Ain1[e] = ain;
    const int jc = 64*e + u0;
    #pragma unroll
    for (int r = 0; r < 4; r++){
      b1c[e][r] = bih1[jc+r] + bhh1[jc+r];
      b2c[e][r] = bih2[jc+r] + bhh2[jc+r];
    }
  }

  float c1[4], c2[4], c1r[4];

  auto lstm1_step = [&](short* S, float* cst, int rb, int wb, int slot, bool relu_out){
    bf16x8 Bh0 = *(const bf16x8*)&S[FB(rb,0,0)+rdo];
    bf16x8 Bl0 = *(const bf16x8*)&S[FB(rb,1,0)+rdo];
    bf16x8 Bh1 = *(const bf16x8*)&S[FB(rb,0,1)+rdo];
    bf16x8 Bl1 = *(const bf16x8*)&S[FB(rb,1,1)+rdo];
    bf16x8 bin = {0,0,0,0,0,0,0,0};
    { float xv = win_s[slot][n]; uint32_t xh, xl; split_t(xv, xh, xl);
      if (q == 0){ bin[0] = (short)xh; bin[1] = (short)xl; bin[2] = (short)xh; } }
    f32x4 acc[4];
    #pragma unroll
    for (int e = 0; e < 4; e++){
      f32x4 a = b1c[e];
      a = mfma16(A1hi[e][0], Bh0, a);
      a = mfma16(A1hi[e][0], Bl0, a);
      a = mfma16(A1lo[e][0], Bh0, a);
      a = mfma16(A1hi[e][1], Bh1, a);
      a = mfma16(A1hi[e][1], Bl1, a);
      a = mfma16(A1lo[e][1], Bh1, a);
      a = mfma16(Ain1[e], bin, a);
      acc[e] = a;
    }
    float hn[4];
    #pragma unroll
    for (int r = 0; r < 4; r++){
      float cn = __builtin_fmaf(sigm(acc[1][r]), cst[r], sigtanh(acc[0][r], acc[2][r]));
      cst[r] = cn;
      hn[r] = sigtanh(acc[3][r], cn);
    }
    uint32_t ph[4], pl[4];
    #pragma unroll
    for (int r = 0; r < 4; r++) split_t(hn[r], ph[r], pl[r]);
    *(uint2*)&S[FB(wb,0,kt_)+wro] = make_uint2(ph[0] | (ph[1]<<16), ph[2] | (ph[3]<<16));
    *(uint2*)&S[FB(wb,1,kt_)+wro] = make_uint2(pl[0] | (pl[1]<<16), pl[2] | (pl[3]<<16));
    if (relu_out){
      uint32_t sh[4], sl[4];
      #pragma unroll
      for (int r = 0; r < 4; r++){ bool pos = hn[r] > 0.0f; sh[r] = pos ? ph[r] : 0u; sl[r] = pos ? pl[r] : 0u; }
      *(uint2*)&rlf[FB(rb,0,kt_)+wro] = make_uint2(sh[0] | (sh[1]<<16), sh[2] | (sh[3]<<16));
      *(uint2*)&rlf[FB(rb,1,kt_)+wro] = make_uint2(sl[0] | (sl[1]<<16), sl[2] | (sl[3]<<16));
    }
  };

  auto lstm2_core = [&](bf16x8 L1h0, bf16x8 L1l0, bf16x8 L1h1, bf16x8 L1l1,
                        int rbuf, int wbuf, bool last){
    bf16x8 L2h0 = *(const bf16x8*)&aS[FB(rbuf,0,0)+rdo];
    bf16x8 L2l0 = *(const bf16x8*)&aS[FB(rbuf,1,0)+rdo];
    bf16x8 L2h1 = *(const bf16x8*)&aS[FB(rbuf,0,1)+rdo];
    bf16x8 L2l1 = *(const bf16x8*)&aS[FB(rbuf,1,1)+rdo];
    f32x4 acc[4];
    #pragma unroll
    for (int e = 0; e < 4; e++){
      f32x4 a = b2c[e];
      a = mfma16(A2hi[e][0], L1h0, a);
      a = mfma16(A2hi[e][0], L1l0, a);
      a = mfma16(A2lo[e][0], L1h0, a);
      a = mfma16(A2hi[e][1], L1h1, a);
      a = mfma16(A2hi[e][1], L1l1, a);
      a = mfma16(A2lo[e][1], L1h1, a);
      a = mfma16(A2hi[e][2], L2h0, a);
      a = mfma16(A2hi[e][2], L2l0, a);
      a = mfma16(A2lo[e][2], L2h0, a);
      a = mfma16(A2hi[e][3], L2h1, a);
      a = mfma16(A2hi[e][3], L2l1, a);
      a = mfma16(A2lo[e][3], L2h1, a);
      acc[e] = a;
    }
    float hn[4];
    #pragma unroll
    for (int r = 0; r < 4; r++){
      float cn = __builtin_fmaf(sigm(acc[1][r]), c2[r], sigtanh(acc[0][r], acc[2][r]));
      c2[r] = cn;
      hn[r] = sigtanh(acc[3][r], cn);
    }
    if (!last){
      uint32_t ph[4], pl[4];
      #pragma unroll
      for (int r = 0; r < 4; r++) split_t(hn[r], ph[r], pl[r]);
      *(uint2*)&aS[FB(wbuf,0,kt_)+wro] = make_uint2(ph[0] | (ph[1]<<16), ph[2] | (ph[3]<<16));
      *(uint2*)&aS[FB(wbuf,1,kt_)+wro] = make_uint2(pl[0] | (pl[1]<<16), pl[2] | (pl[3]<<16));
    } else {
      #pragma unroll
      for (int r = 0; r < 4; r++) Hlast[n][u0 + r] = fmaxf(hn[r], 0.0f);
    }
  };

  for (int s = 0; s < NSTEPS; s++){
    { int* p = (int*)&aS[0];
      for (int i = tid; i < BUF_INTS; i += 256) p[i] = 0; }
    #pragma unroll
    for (int r = 0; r < 4; r++) c1[r] = 0.0f;
    int slot = s;
    for (int t = 0; t < WIN; t++){
      __syncthreads();
      lstm1_step(aS, c1, t & 1, (t & 1) ^ 1, slot, false);
      slot++; if (slot == WIN) slot = 0;
    }
    #pragma unroll
    for (int r = 0; r < 4; r++){ c2[r] = c1[r]; c1r[r] = 0.0f; }
    { int* p = (int*)&r1f[0];
      for (int i = tid; i < BUF_INTS; i += 256) p[i] = 0; }
    slot = s;
    __syncthreads();
    lstm1_step(r1f, c1r, 0, 1, slot, true);
    slot++;
    for (int i = 1; i < WIN; i++){
      __syncthreads();
      const int rb = i & 1, wb = rb ^ 1;
      lstm1_step(r1f, c1r, rb, wb, slot, true);
      bf16x8 L1h0 = *(const bf16x8*)&rlf[FB(wb,0,0)+rdo];
      bf16x8 L1l0 = *(const bf16x8*)&rlf[FB(wb,1,0)+rdo];
      bf16x8 L1h1 = *(const bf16x8*)&rlf[FB(wb,0,1)+rdo];
      bf16x8 L1l1 = *(const bf16x8*)&rlf[FB(wb,1,1)+rdo];
      lstm2_core(L1h0, L1l0, L1h1, L1l1, wb, rb, false);
      slot++; if (slot == WIN) slot = 0;
    }
    __syncthreads();
    {
      const int rb = (WIN - 1) & 1;
      bf16x8 L1h0 = *(const bf16x8*)&rlf[FB(rb,0,0)+rdo];
      bf16x8 L1l0 = *(const bf16x8*)&rlf[FB(rb,1,0)+rdo];
      bf16x8 L1h1 = *(const bf16x8*)&rlf[FB(rb,0,1)+rdo];
      bf16x8 L1l1 = *(const bf16x8*)&rlf[FB(rb,1,1)+rdo];
      lstm2_core(L1h0, L1l0, L1h1, L1l1, rb, 0, true);
    }
    __syncthreads();
    {
      float o4[4];
      #pragma unroll
      for (int bi = 0; bi < 4; bi++){
        const int b = 4*wv + bi;
        float a1 = fc1b_r;
        #pragma unroll
        for (int k4 = 0; k4 < 16; k4++){
          const float* wp = &fc1w_s[ln*68 + k4*4];
          const float* hp = &Hlast[b][k4*4];
          a1 += wp[0]*hp[0] + wp[1]*hp[1] + wp[2]*hp[2] + wp[3]*hp[3];
        }
        a1 += dval_s[b] * fc1w_s[ln*68 + 64];
        float v = a1 * fc2w_r;
        #pragma unroll
        for (int off = 32; off > 0; off >>= 1) v += __shfl_xor(v, off);
        o4[bi] = v + fc2b_r;
      }
      if (ln == 0){
        #pragma unroll
        for (int bi = 0; bi < 4; bi++){
          const int b = 4*wv + bi;
          out[(bg0 + b)*24 + s] = o4[bi];
          win_s[s % WIN][b] = o4[bi];
        }
      }
    }
  }
}

extern "C" void kernel_launch(void* const* d_in, const int* in_sizes, int n_in,
                              void* d_out, int out_size, void* d_ws, size_t ws_size,
                              hipStream_t stream) {
  (void)in_sizes; (void)n_in; (void)out_size;
  const size_t need = (size_t)NBLK * WIN * 2048 * sizeof(short);   // ~176 MB
  if (ws_size >= need){
    lstm_fused_kernel<<<dim3(NBLK), dim3(NT), 0, stream>>>(
        (const float*)d_in[0], (const float*)d_in[1], (const float*)d_in[2],
        (const float*)d_in[3], (const float*)d_in[4], (const float*)d_in[5],
        (const float*)d_in[6], (const float*)d_in[7], (const float*)d_in[8],
        (const float*)d_in[9], (const float*)d_in[10], (const float*)d_in[11],
        (const float*)d_in[12], (float*)d_out, (short*)d_ws);
  } else {
    lstm_fallback_kernel<<<dim3(NBLK), dim3(256), 0, stream>>>(
        (const float*)d_in[0], (const float*)d_in[1], (const float*)d_in[2],
        (const float*)d_in[3], (const float*)d_in[4], (const float*)d_in[5],
        (const float*)d_in[6], (const float*)d_in[7], (const float*)d_in[8],
        (const float*)d_in[9], (const float*)d_in[10], (const float*)d_in[11],
        (const float*)d_in[12], (float*)d_out);
  }
}